// Round 2
// baseline (3711.980 us; speedup 1.0000x reference)
//
#include <hip/hip_runtime.h>

#define NEG_INF -1e10f

typedef unsigned int uint;
typedef unsigned short u16;
typedef __bf16 bf16x8_t __attribute__((ext_vector_type(8)));
typedef float f32x4_t __attribute__((ext_vector_type(4)));

// ---------- helpers ----------
__device__ __forceinline__ u16 f2bf(float f) {
    uint u = __float_as_uint(f);
    u += 0x7FFFu + ((u >> 16) & 1u);          // round-to-nearest-even
    return (u16)(u >> 16);
}
__device__ __forceinline__ float bf2f(u16 h) {
    return __uint_as_float(((uint)h) << 16);
}
__device__ __forceinline__ void gload_lds16(const void* g, void* l) {
    __builtin_amdgcn_global_load_lds(
        (const __attribute__((address_space(1))) uint*)g,
        (__attribute__((address_space(3))) uint*)l, 16, 0, 0);
}

// ---------- stage 0a: fp32 -> (hi,lo) bf16 split ----------
__global__ __launch_bounds__(256) void convert_hilo(
    const float4* __restrict__ src, ushort4* __restrict__ hi,
    ushort4* __restrict__ lo, int n4)
{
    int idx = blockIdx.x * 256 + threadIdx.x;
    const int stride = gridDim.x * 256;
    for (; idx < n4; idx += stride) {
        float4 x = src[idx];
        ushort4 h, l;
        h.x = f2bf(x.x); l.x = f2bf(x.x - bf2f(h.x));
        h.y = f2bf(x.y); l.y = f2bf(x.y - bf2f(h.y));
        h.z = f2bf(x.z); l.z = f2bf(x.z - bf2f(h.z));
        h.w = f2bf(x.w); l.w = f2bf(x.w - bf2f(h.w));
        hi[idx] = h; lo[idx] = l;
    }
}

// ---------- stage 0b: V [B][2048][1024] fp32 -> VT [B][1024][2048] bf16 ----------
__global__ __launch_bounds__(256) void transpose_convert(
    const float* __restrict__ V, u16* __restrict__ VT)
{
    __shared__ float tile[64][65];
    const int t  = threadIdx.x;
    const int d0 = blockIdx.x * 64;            // dim 1024
    const int k0 = blockIdx.y * 64;            // dim 2048
    const float* Vb = V + (size_t)blockIdx.z * (2048 * 1024);
    u16* VTb = VT + (size_t)blockIdx.z * (1024 * 2048);
#pragma unroll
    for (int i = 0; i < 4; ++i) {
        int f = i * 256 + t;
        int r = f >> 4, c4 = f & 15;
        float4 v = *(const float4*)&Vb[(size_t)(k0 + r) * 1024 + d0 + c4 * 4];
        tile[r][c4 * 4 + 0] = v.x;
        tile[r][c4 * 4 + 1] = v.y;
        tile[r][c4 * 4 + 2] = v.z;
        tile[r][c4 * 4 + 3] = v.w;
    }
    __syncthreads();
#pragma unroll
    for (int i = 0; i < 4; ++i) {
        int f = i * 256 + t;
        int d = f >> 4, c4 = f & 15;
        ushort4 o;
        o.x = f2bf(tile[c4 * 4 + 0][d]);
        o.y = f2bf(tile[c4 * 4 + 1][d]);
        o.z = f2bf(tile[c4 * 4 + 2][d]);
        o.w = f2bf(tile[c4 * 4 + 3][d]);
        *(ushort4*)&VTb[(size_t)(d0 + d) * 2048 + k0 + c4 * 4] = o;
    }
}

// ---------- GEMM (m97 structure): C[m][n] = sum_t sum_k A_t[m][k]*B_t[n][k] ----------
// 128x128 tile, BK=32, 4 waves, each wave 64x64 via 4x4 frags of 16x16x32 MFMA.
template<int NT>
__global__ __launch_bounds__(256, 2) void gemm_bt(
    const u16* __restrict__ A0, const u16* __restrict__ B0,
    const u16* __restrict__ A1, const u16* __restrict__ B1,
    const u16* __restrict__ A2, const u16* __restrict__ B2,
    float* __restrict__ C, int M, int N, int K,
    size_t sA, size_t sB, size_t sC)
{
    __shared__ u16 As[128 * 32];
    __shared__ u16 Bs[128 * 32];
    const int tid  = threadIdx.x;
    const int lane = tid & 63;
    const int w    = tid >> 6;
    const int wm   = w >> 1, wn = w & 1;
    const int m0   = blockIdx.y * 128, n0 = blockIdx.x * 128;
    const size_t z = blockIdx.z;

    const u16* Ap[3] = { A0 + z * sA, A1 + z * sA, A2 + z * sA };
    const u16* Bp[3] = { B0 + z * sB, B1 + z * sB, B2 + z * sB };

    f32x4_t acc[4][4] = {};

    const int lr = lane & 15;
    const int lk = (lane >> 4) * 8;

#pragma unroll
    for (int term = 0; term < NT; ++term) {
        const u16* A = Ap[term];
        const u16* B = Bp[term];
        for (int kk = 0; kk < K; kk += 32) {
            // stage 128x32 A and B tiles: 2 issues each, 16B/lane
#pragma unroll
            for (int i = 0; i < 2; ++i) {
                int e = (i * 256 + tid) * 8;
                int r = e >> 5, c = e & 31;
                gload_lds16(&A[(size_t)(m0 + r) * K + kk + c], &As[i * 2048 + w * 512]);
                gload_lds16(&B[(size_t)(n0 + r) * K + kk + c], &Bs[i * 2048 + w * 512]);
            }
            __syncthreads();   // drains vmcnt before any wave reads LDS

            bf16x8_t af[4], bfr[4];
#pragma unroll
            for (int m = 0; m < 4; ++m)
                af[m] = *(const bf16x8_t*)&As[(wm * 64 + m * 16 + lr) * 32 + lk];
#pragma unroll
            for (int n = 0; n < 4; ++n)
                bfr[n] = *(const bf16x8_t*)&Bs[(wn * 64 + n * 16 + lr) * 32 + lk];
#pragma unroll
            for (int m = 0; m < 4; ++m)
#pragma unroll
                for (int n = 0; n < 4; ++n)
                    acc[m][n] = __builtin_amdgcn_mfma_f32_16x16x32_bf16(
                        af[m], bfr[n], acc[m][n], 0, 0, 0);
            __syncthreads();   // all reads done before next-tile overwrite
        }
    }

    float* Cb = C + z * sC;
    const int lg = lane >> 4;
#pragma unroll
    for (int m = 0; m < 4; ++m)
#pragma unroll
        for (int n = 0; n < 4; ++n) {
            const int col  = n0 + wn * 64 + n * 16 + lr;
            const int rowb = m0 + wm * 64 + m * 16 + lg * 4;
#pragma unroll
            for (int r = 0; r < 4; ++r)
                Cb[(size_t)(rowb + r) * N + col] = acc[m][n][r];
        }
}

// ---------- stage 2: masked row softmax, S fp32 -> P bf16 ----------
__global__ __launch_bounds__(256) void softmax_mask(
    const float* __restrict__ S, const int* __restrict__ mask,
    u16* __restrict__ P)
{
    const int lane = threadIdx.x & 63;
    const int wave = threadIdx.x >> 6;
    const int row  = blockIdx.x * 4 + wave;    // [0, B*2048)
    const int b    = row >> 11;
    const float* Sr = S + (size_t)row * 2048;
    const int* mb   = mask + b * 2048;

    float4 s[8];
    float m = -INFINITY;
#pragma unroll
    for (int i = 0; i < 8; ++i) {
        int k = i * 256 + lane * 4;
        float4 v = *(const float4*)&Sr[k];
        int4 mk  = *(const int4*)&mb[k];
        v.x = mk.x ? v.x : NEG_INF;
        v.y = mk.y ? v.y : NEG_INF;
        v.z = mk.z ? v.z : NEG_INF;
        v.w = mk.w ? v.w : NEG_INF;
        s[i] = v;
        m = fmaxf(m, fmaxf(fmaxf(v.x, v.y), fmaxf(v.z, v.w)));
    }
#pragma unroll
    for (int off = 32; off > 0; off >>= 1)
        m = fmaxf(m, __shfl_xor(m, off, 64));
    float sum = 0.f;
#pragma unroll
    for (int i = 0; i < 8; ++i) {
        s[i].x = __expf(s[i].x - m); sum += s[i].x;
        s[i].y = __expf(s[i].y - m); sum += s[i].y;
        s[i].z = __expf(s[i].z - m); sum += s[i].z;
        s[i].w = __expf(s[i].w - m); sum += s[i].w;
    }
#pragma unroll
    for (int off = 32; off > 0; off >>= 1)
        sum += __shfl_xor(sum, off, 64);
    const float inv = 1.f / sum;
    u16* Pr = P + (size_t)row * 2048;
#pragma unroll
    for (int i = 0; i < 8; ++i) {
        int k = i * 256 + lane * 4;
        ushort4 o;
        o.x = f2bf(s[i].x * inv);
        o.y = f2bf(s[i].y * inv);
        o.z = f2bf(s[i].z * inv);
        o.w = f2bf(s[i].w * inv);
        *(ushort4*)&Pr[k] = o;
    }
}

// ---------- fallback (R1 verified fp32 kernel, used only if ws too small) ----------
__global__ __launch_bounds__(256, 2) void attn_fp32_flash(
    const float* __restrict__ hidden, const float* __restrict__ keys,
    const float* __restrict__ values, const int* __restrict__ mask,
    float* __restrict__ out)
{
    const int lane = threadIdx.x & 63;
    const int wave = threadIdx.x >> 6;
    const int blk  = blockIdx.x;
    const int b    = blk >> 7;
    const int q0   = (blk & 127) * 16 + wave * 4;
    float4 q[4][4]; float4 o[4][4]; float m[4], s[4];
    const float4* hp = (const float4*)(hidden + ((size_t)b * 2048 + q0) * 1024);
#pragma unroll
    for (int r = 0; r < 4; ++r) {
#pragma unroll
        for (int j = 0; j < 4; ++j) {
            q[r][j] = hp[r * 256 + j * 64 + lane];
            o[r][j] = make_float4(0.f, 0.f, 0.f, 0.f);
        }
        m[r] = -INFINITY; s[r] = 0.f;
    }
    const float4* kp = (const float4*)(keys   + (size_t)b * 2048 * 1024);
    const float4* vp = (const float4*)(values + (size_t)b * 2048 * 1024);
    const int*    mp = mask + b * 2048;
    for (int k = 0; k < 2048; ++k) {
        float4 kv[4];
#pragma unroll
        for (int j = 0; j < 4; ++j) kv[j] = kp[k * 256 + j * 64 + lane];
        float sc[4];
#pragma unroll
        for (int r = 0; r < 4; ++r) {
            float p = 0.f;
#pragma unroll
            for (int j = 0; j < 4; ++j)
                p += q[r][j].x * kv[j].x + q[r][j].y * kv[j].y +
                     q[r][j].z * kv[j].z + q[r][j].w * kv[j].w;
            sc[r] = p;
        }
#pragma unroll
        for (int r = 0; r < 4; ++r)
#pragma unroll
            for (int off = 32; off > 0; off >>= 1)
                sc[r] += __shfl_xor(sc[r], off, 64);
        const int mk = mp[k];
        float4 vv[4];
#pragma unroll
        for (int j = 0; j < 4; ++j) vv[j] = vp[k * 256 + j * 64 + lane];
#pragma unroll
        for (int r = 0; r < 4; ++r) {
            float score = mk ? sc[r] : NEG_INF;
            if (score > m[r]) {
                float scale = __expf(m[r] - score);
                m[r] = score; s[r] *= scale;
#pragma unroll
                for (int j = 0; j < 4; ++j) {
                    o[r][j].x *= scale; o[r][j].y *= scale;
                    o[r][j].z *= scale; o[r][j].w *= scale;
                }
            }
            float e = __expf(score - m[r]);
            s[r] += e;
#pragma unroll
            for (int j = 0; j < 4; ++j) {
                o[r][j].x += e * vv[j].x; o[r][j].y += e * vv[j].y;
                o[r][j].z += e * vv[j].z; o[r][j].w += e * vv[j].w;
            }
        }
    }
    float4* op = (float4*)(out + ((size_t)b * 2048 + q0) * 1024);
#pragma unroll
    for (int r = 0; r < 4; ++r) {
        float inv = 1.f / s[r];
#pragma unroll
        for (int j = 0; j < 4; ++j) {
            float4 t = o[r][j];
            t.x *= inv; t.y *= inv; t.z *= inv; t.w *= inv;
            op[r * 256 + j * 64 + lane] = t;
        }
    }
}

extern "C" void kernel_launch(void* const* d_in, const int* in_sizes, int n_in,
                              void* d_out, int out_size, void* d_ws, size_t ws_size,
                              hipStream_t stream) {
    const float* hidden = (const float*)d_in[0];
    const float* keys   = (const float*)d_in[1];
    const float* values = (const float*)d_in[2];
    const int*   mask   = (const int*)d_in[3];
    float* out = (float*)d_out;

    const size_t SZ_BF = 8ull * 2048 * 1024 * 2;                 // 32 MiB per bf16 tensor
    const size_t SZ_S  = 8ull * 2048 * 2048 * 4;                 // 128 MiB fp32 scores
    const size_t SZ_P  = 8ull * 2048 * 2048 * 2;                 // 64 MiB bf16 weights
    const size_t need  = 5 * SZ_BF + SZ_S + SZ_P;                // 352 MiB

    if (ws_size < need) {
        attn_fp32_flash<<<1024, 256, 0, stream>>>(hidden, keys, values, mask, out);
        return;
    }

    char* ws = (char*)d_ws;
    u16*   Qh = (u16*)(ws);
    u16*   Ql = (u16*)(ws + SZ_BF);
    u16*   Kh = (u16*)(ws + 2 * SZ_BF);
    u16*   Kl = (u16*)(ws + 3 * SZ_BF);
    u16*   VT = (u16*)(ws + 4 * SZ_BF);
    float* S  = (float*)(ws + 5 * SZ_BF);
    u16*   P  = (u16*)(ws + 5 * SZ_BF + SZ_S);

    const int n4 = 8 * 2048 * 1024 / 4;
    convert_hilo<<<2048, 256, 0, stream>>>((const float4*)hidden,
                                           (ushort4*)Qh, (ushort4*)Ql, n4);
    convert_hilo<<<2048, 256, 0, stream>>>((const float4*)keys,
                                           (ushort4*)Kh, (ushort4*)Kl, n4);
    transpose_convert<<<dim3(16, 32, 8), 256, 0, stream>>>(values, VT);

    // S = Qh*Kh^T + Qh*Kl^T + Ql*Kh^T
    gemm_bt<3><<<dim3(16, 16, 8), 256, 0, stream>>>(
        Qh, Kh, Qh, Kl, Ql, Kh, S, 2048, 2048, 1024,
        (size_t)2048 * 1024, (size_t)2048 * 1024, (size_t)2048 * 2048);

    softmax_mask<<<4096, 256, 0, stream>>>(S, mask, P);

    // out = P * VT^T
    gemm_bt<1><<<dim3(8, 16, 8), 256, 0, stream>>>(
        P, VT, P, VT, P, VT, out, 2048, 1024, 2048,
        (size_t)2048 * 2048, (size_t)1024 * 2048, (size_t)2048 * 1024);
}

// Round 3
// 943.799 us; speedup vs baseline: 3.9330x; 3.9330x over previous
//
#include <hip/hip_runtime.h>

#define NEG_INF -1e10f
#define B_   8
#define LQ_  2048
#define LK_  2048
#define D_   1024

typedef unsigned int uint;
typedef unsigned short u16;
typedef __bf16 bf16x8_t __attribute__((ext_vector_type(8)));
typedef float f32x4_t __attribute__((ext_vector_type(4)));

// ---------- helpers ----------
__device__ __forceinline__ u16 f2bf(float f) {
    uint u = __float_as_uint(f);
    u += 0x7FFFu + ((u >> 16) & 1u);          // round-to-nearest-even
    return (u16)(u >> 16);
}
__device__ __forceinline__ float bf2f(u16 h) {
    return __uint_as_float(((uint)h) << 16);
}
__device__ __forceinline__ void gload_lds16(const void* g, void* l) {
    __builtin_amdgcn_global_load_lds(
        (const __attribute__((address_space(1))) uint*)g,
        (__attribute__((address_space(3))) uint*)l, 16, 0, 0);
}

// ---------- fp32 -> (hi,lo) bf16 split ----------
__global__ __launch_bounds__(256) void convert_hilo(
    const float4* __restrict__ src, ushort4* __restrict__ hi,
    ushort4* __restrict__ lo, int n4)
{
    int idx = blockIdx.x * 256 + threadIdx.x;
    const int stride = gridDim.x * 256;
    for (; idx < n4; idx += stride) {
        float4 x = src[idx];
        ushort4 h, l;
        h.x = f2bf(x.x); l.x = f2bf(x.x - bf2f(h.x));
        h.y = f2bf(x.y); l.y = f2bf(x.y - bf2f(h.y));
        h.z = f2bf(x.z); l.z = f2bf(x.z - bf2f(h.z));
        h.w = f2bf(x.w); l.w = f2bf(x.w - bf2f(h.w));
        hi[idx] = h; lo[idx] = l;
    }
}

// ---------- V [z][2048][1024] fp32 -> VT [z][1024][2048] bf16 ----------
__global__ __launch_bounds__(256) void transpose_convert(
    const float* __restrict__ V, u16* __restrict__ VT)
{
    __shared__ float tile[64][65];
    const int t  = threadIdx.x;
    const int d0 = blockIdx.x * 64;
    const int k0 = blockIdx.y * 64;
    const float* Vb = V + (size_t)blockIdx.z * (LK_ * D_);
    u16* VTb = VT + (size_t)blockIdx.z * (D_ * LK_);
#pragma unroll
    for (int i = 0; i < 4; ++i) {
        int f = i * 256 + t;
        int r = f >> 4, c4 = f & 15;
        float4 v = *(const float4*)&Vb[(size_t)(k0 + r) * D_ + d0 + c4 * 4];
        tile[r][c4 * 4 + 0] = v.x;
        tile[r][c4 * 4 + 1] = v.y;
        tile[r][c4 * 4 + 2] = v.z;
        tile[r][c4 * 4 + 3] = v.w;
    }
    __syncthreads();
#pragma unroll
    for (int i = 0; i < 4; ++i) {
        int f = i * 256 + t;
        int d = f >> 4, c4 = f & 15;
        ushort4 o;
        o.x = f2bf(tile[c4 * 4 + 0][d]);
        o.y = f2bf(tile[c4 * 4 + 1][d]);
        o.z = f2bf(tile[c4 * 4 + 2][d]);
        o.w = f2bf(tile[c4 * 4 + 3][d]);
        *(ushort4*)&VTb[(size_t)(d0 + d) * LK_ + k0 + c4 * 4] = o;
    }
}

// ---------- GEMM (m97 structure): C = sum_t A_t * B_t^T ----------
template<int NT>
__global__ __launch_bounds__(256, 2) void gemm_bt(
    const u16* __restrict__ A0, const u16* __restrict__ B0,
    const u16* __restrict__ A1, const u16* __restrict__ B1,
    const u16* __restrict__ A2, const u16* __restrict__ B2,
    float* __restrict__ C, int N, int K,
    size_t sA, size_t sB, size_t sC)
{
    __shared__ u16 As[128 * 32];
    __shared__ u16 Bs[128 * 32];
    const int tid  = threadIdx.x;
    const int lane = tid & 63;
    const int w    = tid >> 6;
    const int wm   = w >> 1, wn = w & 1;
    const int m0   = blockIdx.y * 128, n0 = blockIdx.x * 128;
    const size_t z = blockIdx.z;

    const u16* Ap[3] = { A0 + z * sA, A1 + z * sA, A2 + z * sA };
    const u16* Bp[3] = { B0 + z * sB, B1 + z * sB, B2 + z * sB };

    f32x4_t acc[4][4] = {};
    const int lr = lane & 15;
    const int lk = (lane >> 4) * 8;

#pragma unroll
    for (int term = 0; term < NT; ++term) {
        const u16* A = Ap[term];
        const u16* B = Bp[term];
        for (int kk = 0; kk < K; kk += 32) {
#pragma unroll
            for (int i = 0; i < 2; ++i) {
                int e = (i * 256 + tid) * 8;
                int r = e >> 5, c = e & 31;
                gload_lds16(&A[(size_t)(m0 + r) * K + kk + c], &As[i * 2048 + w * 512]);
                gload_lds16(&B[(size_t)(n0 + r) * K + kk + c], &Bs[i * 2048 + w * 512]);
            }
            __syncthreads();

            bf16x8_t af[4], bfr[4];
#pragma unroll
            for (int m = 0; m < 4; ++m)
                af[m] = *(const bf16x8_t*)&As[(wm * 64 + m * 16 + lr) * 32 + lk];
#pragma unroll
            for (int n = 0; n < 4; ++n)
                bfr[n] = *(const bf16x8_t*)&Bs[(wn * 64 + n * 16 + lr) * 32 + lk];
#pragma unroll
            for (int m = 0; m < 4; ++m)
#pragma unroll
                for (int n = 0; n < 4; ++n)
                    acc[m][n] = __builtin_amdgcn_mfma_f32_16x16x32_bf16(
                        af[m], bfr[n], acc[m][n], 0, 0, 0);
            __syncthreads();
        }
    }

    float* Cb = C + z * sC;
    const int lg = lane >> 4;
#pragma unroll
    for (int m = 0; m < 4; ++m)
#pragma unroll
        for (int n = 0; n < 4; ++n) {
            const int col  = n0 + wn * 64 + n * 16 + lr;
            const int rowb = m0 + wm * 64 + m * 16 + lg * 4;
#pragma unroll
            for (int r = 0; r < 4; ++r)
                Cb[(size_t)(rowb + r) * N + col] = acc[m][n][r];
        }
}

// ---------- masked row softmax over one batch's chunk: S fp32 -> P bf16 ----------
// mb = mask row for this batch (shared by all rows in the chunk).
__global__ __launch_bounds__(256) void softmax_mask(
    const float* __restrict__ S, const int* __restrict__ mb,
    u16* __restrict__ P)
{
    const int lane = threadIdx.x & 63;
    const int wave = threadIdx.x >> 6;
    const int row  = blockIdx.x * 4 + wave;
    const float* Sr = S + (size_t)row * LK_;

    float4 s[8];
    float m = -INFINITY;
#pragma unroll
    for (int i = 0; i < 8; ++i) {
        int k = i * 256 + lane * 4;
        float4 v = *(const float4*)&Sr[k];
        int4 mk  = *(const int4*)&mb[k];
        v.x = mk.x ? v.x : NEG_INF;
        v.y = mk.y ? v.y : NEG_INF;
        v.z = mk.z ? v.z : NEG_INF;
        v.w = mk.w ? v.w : NEG_INF;
        s[i] = v;
        m = fmaxf(m, fmaxf(fmaxf(v.x, v.y), fmaxf(v.z, v.w)));
    }
#pragma unroll
    for (int off = 32; off > 0; off >>= 1)
        m = fmaxf(m, __shfl_xor(m, off, 64));
    float sum = 0.f;
#pragma unroll
    for (int i = 0; i < 8; ++i) {
        s[i].x = __expf(s[i].x - m); sum += s[i].x;
        s[i].y = __expf(s[i].y - m); sum += s[i].y;
        s[i].z = __expf(s[i].z - m); sum += s[i].z;
        s[i].w = __expf(s[i].w - m); sum += s[i].w;
    }
#pragma unroll
    for (int off = 32; off > 0; off >>= 1)
        sum += __shfl_xor(sum, off, 64);
    const float inv = 1.f / sum;
    u16* Pr = P + (size_t)row * LK_;
#pragma unroll
    for (int i = 0; i < 8; ++i) {
        int k = i * 256 + lane * 4;
        ushort4 o;
        o.x = f2bf(s[i].x * inv);
        o.y = f2bf(s[i].y * inv);
        o.z = f2bf(s[i].z * inv);
        o.w = f2bf(s[i].w * inv);
        *(ushort4*)&Pr[k] = o;
    }
}

// ---------- fallback (verified R1 fp32 kernel) ----------
__global__ __launch_bounds__(256, 2) void attn_fp32_flash(
    const float* __restrict__ hidden, const float* __restrict__ keys,
    const float* __restrict__ values, const int* __restrict__ mask,
    float* __restrict__ out)
{
    const int lane = threadIdx.x & 63;
    const int wave = threadIdx.x >> 6;
    const int blk  = blockIdx.x;
    const int b    = blk >> 7;
    const int q0   = (blk & 127) * 16 + wave * 4;
    float4 q[4][4]; float4 o[4][4]; float m[4], s[4];
    const float4* hp = (const float4*)(hidden + ((size_t)b * LQ_ + q0) * D_);
#pragma unroll
    for (int r = 0; r < 4; ++r) {
#pragma unroll
        for (int j = 0; j < 4; ++j) {
            q[r][j] = hp[r * 256 + j * 64 + lane];
            o[r][j] = make_float4(0.f, 0.f, 0.f, 0.f);
        }
        m[r] = -INFINITY; s[r] = 0.f;
    }
    const float4* kp = (const float4*)(keys   + (size_t)b * LK_ * D_);
    const float4* vp = (const float4*)(values + (size_t)b * LK_ * D_);
    const int*    mp = mask + b * LK_;
    for (int k = 0; k < LK_; ++k) {
        float4 kv[4];
#pragma unroll
        for (int j = 0; j < 4; ++j) kv[j] = kp[k * 256 + j * 64 + lane];
        float sc[4];
#pragma unroll
        for (int r = 0; r < 4; ++r) {
            float p = 0.f;
#pragma unroll
            for (int j = 0; j < 4; ++j)
                p += q[r][j].x * kv[j].x + q[r][j].y * kv[j].y +
                     q[r][j].z * kv[j].z + q[r][j].w * kv[j].w;
            sc[r] = p;
        }
#pragma unroll
        for (int r = 0; r < 4; ++r)
#pragma unroll
            for (int off = 32; off > 0; off >>= 1)
                sc[r] += __shfl_xor(sc[r], off, 64);
        const int mk = mp[k];
        float4 vv[4];
#pragma unroll
        for (int j = 0; j < 4; ++j) vv[j] = vp[k * 256 + j * 64 + lane];
#pragma unroll
        for (int r = 0; r < 4; ++r) {
            float score = mk ? sc[r] : NEG_INF;
            if (score > m[r]) {
                float scale = __expf(m[r] - score);
                m[r] = score; s[r] *= scale;
#pragma unroll
                for (int j = 0; j < 4; ++j) {
                    o[r][j].x *= scale; o[r][j].y *= scale;
                    o[r][j].z *= scale; o[r][j].w *= scale;
                }
            }
            float e = __expf(score - m[r]);
            s[r] += e;
#pragma unroll
            for (int j = 0; j < 4; ++j) {
                o[r][j].x += e * vv[j].x; o[r][j].y += e * vv[j].y;
                o[r][j].z += e * vv[j].z; o[r][j].w += e * vv[j].w;
            }
        }
    }
    float4* op = (float4*)(out + ((size_t)b * LQ_ + q0) * D_);
#pragma unroll
    for (int r = 0; r < 4; ++r) {
        float inv = 1.f / s[r];
#pragma unroll
        for (int j = 0; j < 4; ++j) {
            float4 t = o[r][j];
            t.x *= inv; t.y *= inv; t.z *= inv; t.w *= inv;
            op[r * 256 + j * 64 + lane] = t;
        }
    }
}

extern "C" void kernel_launch(void* const* d_in, const int* in_sizes, int n_in,
                              void* d_out, int out_size, void* d_ws, size_t ws_size,
                              hipStream_t stream) {
    const float* hidden = (const float*)d_in[0];
    const float* keys   = (const float*)d_in[1];
    const float* values = (const float*)d_in[2];
    const int*   mask   = (const int*)d_in[3];
    float* out = (float*)d_out;
    char* ws = (char*)d_ws;

    const size_t TEN   = (size_t)LK_ * D_;        // 2M elems per batch tensor
    const size_t SZ_BF = TEN * 2;                  // 4 MiB bf16 per batch tensor

    // ---- Path A: everything at once (352 MiB) ----
    const size_t SZ_BF_ALL = (size_t)B_ * SZ_BF;
    const size_t SZ_S_ALL  = (size_t)B_ * LQ_ * LK_ * 4;
    const size_t SZ_P_ALL  = (size_t)B_ * LQ_ * LK_ * 2;
    if (ws_size >= 5 * SZ_BF_ALL + SZ_S_ALL + SZ_P_ALL) {
        u16*   Qh = (u16*)(ws);
        u16*   Ql = (u16*)(ws + SZ_BF_ALL);
        u16*   Kh = (u16*)(ws + 2 * SZ_BF_ALL);
        u16*   Kl = (u16*)(ws + 3 * SZ_BF_ALL);
        u16*   VT = (u16*)(ws + 4 * SZ_BF_ALL);
        float* S  = (float*)(ws + 5 * SZ_BF_ALL);
        u16*   P  = (u16*)(ws + 5 * SZ_BF_ALL + SZ_S_ALL);
        const int n4 = B_ * LK_ * D_ / 4;
        convert_hilo<<<2048, 256, 0, stream>>>((const float4*)hidden,
                                               (ushort4*)Qh, (ushort4*)Ql, n4);
        convert_hilo<<<2048, 256, 0, stream>>>((const float4*)keys,
                                               (ushort4*)Kh, (ushort4*)Kl, n4);
        transpose_convert<<<dim3(16, 32, B_), 256, 0, stream>>>(values, VT);
        gemm_bt<3><<<dim3(16, 16, B_), 256, 0, stream>>>(
            Qh, Kh, Qh, Kl, Ql, Kh, S, LK_, D_, TEN, TEN, (size_t)LQ_ * LK_);
        for (int b = 0; b < B_; ++b)
            softmax_mask<<<LQ_ / 4, 256, 0, stream>>>(
                S + (size_t)b * LQ_ * LK_, mask + b * LK_,
                P + (size_t)b * LQ_ * LK_);
        gemm_bt<1><<<dim3(8, 16, B_), 256, 0, stream>>>(
            P, VT, P, VT, P, VT, out, D_, LK_,
            (size_t)LQ_ * LK_, TEN, TEN);
        return;
    }

    // ---- Path B: per-batch / per-q-chunk reuse ----
    int QM = 0;
    for (int qm = 2048; qm >= 128; qm >>= 1) {
        size_t need = 2 * SZ_BF + SZ_BF                 // Kh,Kl,VT
                    + 2 * (size_t)qm * D_ * 2           // Qh,Ql
                    + (size_t)qm * LK_ * 4               // S
                    + (size_t)qm * LK_ * 2;              // P
        if (need <= ws_size) { QM = qm; break; }
    }

    if (QM == 0) {
        attn_fp32_flash<<<1024, 256, 0, stream>>>(hidden, keys, values, mask, out);
        return;
    }

    u16*   Kh = (u16*)(ws);
    u16*   Kl = (u16*)(ws + SZ_BF);
    u16*   VT = (u16*)(ws + 2 * SZ_BF);
    u16*   Qh = (u16*)(ws + 3 * SZ_BF);
    u16*   Ql = (u16*)(ws + 3 * SZ_BF + (size_t)QM * D_ * 2);
    float* S  = (float*)(ws + 3 * SZ_BF + 2 * (size_t)QM * D_ * 2);
    u16*   P  = (u16*)((char*)S + (size_t)QM * LK_ * 4);

    const int n4k = LK_ * D_ / 4;
    const int n4q = QM * D_ / 4;
    const int gq  = n4q / 256 < 2048 ? n4q / 256 : 2048;

    for (int b = 0; b < B_; ++b) {
        convert_hilo<<<2048, 256, 0, stream>>>(
            (const float4*)(keys + (size_t)b * TEN),
            (ushort4*)Kh, (ushort4*)Kl, n4k);
        transpose_convert<<<dim3(16, 32, 1), 256, 0, stream>>>(
            values + (size_t)b * TEN, VT);
        for (int q0 = 0; q0 < LQ_; q0 += QM) {
            convert_hilo<<<gq, 256, 0, stream>>>(
                (const float4*)(hidden + ((size_t)b * LQ_ + q0) * D_),
                (ushort4*)Qh, (ushort4*)Ql, n4q);
            gemm_bt<3><<<dim3(16, QM / 128, 1), 256, 0, stream>>>(
                Qh, Kh, Qh, Kl, Ql, Kh, S, LK_, D_, 0, 0, 0);
            softmax_mask<<<QM / 4, 256, 0, stream>>>(S, mask + b * LK_, P);
            gemm_bt<1><<<dim3(8, QM / 128, 1), 256, 0, stream>>>(
                P, VT, P, VT, P, VT,
                out + ((size_t)b * LQ_ + q0) * D_, D_, LK_, 0, 0, 0);
        }
    }
}

// Round 4
// 459.687 us; speedup vs baseline: 8.0750x; 2.0531x over previous
//
#include <hip/hip_runtime.h>

#define NEG_INF -1e10f
#define B_   8
#define LQ_  2048
#define LK_  2048
#define D_   1024

typedef unsigned int uint;
typedef unsigned short u16;
typedef __bf16 bf16x8_t __attribute__((ext_vector_type(8)));
typedef float f32x4_t __attribute__((ext_vector_type(4)));

// ---------- helpers ----------
__device__ __forceinline__ u16 f2bf(float f) {
    uint u = __float_as_uint(f);
    u += 0x7FFFu + ((u >> 16) & 1u);          // round-to-nearest-even
    return (u16)(u >> 16);
}
__device__ __forceinline__ float bf2f(u16 h) {
    return __uint_as_float(((uint)h) << 16);
}
__device__ __forceinline__ void gload_lds16(const void* g, void* l) {
    __builtin_amdgcn_global_load_lds(
        (const __attribute__((address_space(1))) uint*)g,
        (__attribute__((address_space(3))) uint*)l, 16, 0, 0);
}

// ---------- fp32 -> (hi,lo) bf16 split ----------
__global__ __launch_bounds__(256) void convert_hilo(
    const float4* __restrict__ src, ushort4* __restrict__ hi,
    ushort4* __restrict__ lo, int n4)
{
    int idx = blockIdx.x * 256 + threadIdx.x;
    const int stride = gridDim.x * 256;
    for (; idx < n4; idx += stride) {
        float4 x = src[idx];
        ushort4 h, l;
        h.x = f2bf(x.x); l.x = f2bf(x.x - bf2f(h.x));
        h.y = f2bf(x.y); l.y = f2bf(x.y - bf2f(h.y));
        h.z = f2bf(x.z); l.z = f2bf(x.z - bf2f(h.z));
        h.w = f2bf(x.w); l.w = f2bf(x.w - bf2f(h.w));
        hi[idx] = h; lo[idx] = l;
    }
}

// ---------- V [z][2048][1024] fp32 -> VT [z][1024][2048] bf16 ----------
__global__ __launch_bounds__(256) void transpose_convert(
    const float* __restrict__ V, u16* __restrict__ VT)
{
    __shared__ float tile[64][65];
    const int t  = threadIdx.x;
    const int d0 = blockIdx.x * 64;
    const int k0 = blockIdx.y * 64;
    const float* Vb = V + (size_t)blockIdx.z * (LK_ * D_);
    u16* VTb = VT + (size_t)blockIdx.z * (D_ * LK_);
#pragma unroll
    for (int i = 0; i < 4; ++i) {
        int f = i * 256 + t;
        int r = f >> 4, c4 = f & 15;
        float4 v = *(const float4*)&Vb[(size_t)(k0 + r) * D_ + d0 + c4 * 4];
        tile[r][c4 * 4 + 0] = v.x;
        tile[r][c4 * 4 + 1] = v.y;
        tile[r][c4 * 4 + 2] = v.z;
        tile[r][c4 * 4 + 3] = v.w;
    }
    __syncthreads();
#pragma unroll
    for (int i = 0; i < 4; ++i) {
        int f = i * 256 + t;
        int d = f >> 4, c4 = f & 15;
        ushort4 o;
        o.x = f2bf(tile[c4 * 4 + 0][d]);
        o.y = f2bf(tile[c4 * 4 + 1][d]);
        o.z = f2bf(tile[c4 * 4 + 2][d]);
        o.w = f2bf(tile[c4 * 4 + 3][d]);
        *(ushort4*)&VTb[(size_t)(d0 + d) * LK_ + k0 + c4 * 4] = o;
    }
}

// ---------- GEMM (m97 structure): C = sum_t A_t * B_t^T, z-batched ----------
template<int NT>
__global__ __launch_bounds__(256, 2) void gemm_bt(
    const u16* __restrict__ A0, const u16* __restrict__ B0,
    const u16* __restrict__ A1, const u16* __restrict__ B1,
    const u16* __restrict__ A2, const u16* __restrict__ B2,
    float* __restrict__ C, int N, int K,
    size_t sA, size_t sB, size_t sC)
{
    __shared__ u16 As[128 * 32];
    __shared__ u16 Bs[128 * 32];
    const int tid  = threadIdx.x;
    const int lane = tid & 63;
    const int w    = tid >> 6;
    const int wm   = w >> 1, wn = w & 1;
    const int m0   = blockIdx.y * 128, n0 = blockIdx.x * 128;
    const size_t z = blockIdx.z;

    const u16* Ap[3] = { A0 + z * sA, A1 + z * sA, A2 + z * sA };
    const u16* Bp[3] = { B0 + z * sB, B1 + z * sB, B2 + z * sB };

    f32x4_t acc[4][4] = {};
    const int lr = lane & 15;
    const int lk = (lane >> 4) * 8;

#pragma unroll
    for (int term = 0; term < NT; ++term) {
        const u16* A = Ap[term];
        const u16* B = Bp[term];
        for (int kk = 0; kk < K; kk += 32) {
#pragma unroll
            for (int i = 0; i < 2; ++i) {
                int e = (i * 256 + tid) * 8;
                int r = e >> 5, c = e & 31;
                gload_lds16(&A[(size_t)(m0 + r) * K + kk + c], &As[i * 2048 + w * 512]);
                gload_lds16(&B[(size_t)(n0 + r) * K + kk + c], &Bs[i * 2048 + w * 512]);
            }
            __syncthreads();

            bf16x8_t af[4], bfr[4];
#pragma unroll
            for (int m = 0; m < 4; ++m)
                af[m] = *(const bf16x8_t*)&As[(wm * 64 + m * 16 + lr) * 32 + lk];
#pragma unroll
            for (int n = 0; n < 4; ++n)
                bfr[n] = *(const bf16x8_t*)&Bs[(wn * 64 + n * 16 + lr) * 32 + lk];
#pragma unroll
            for (int m = 0; m < 4; ++m)
#pragma unroll
                for (int n = 0; n < 4; ++n)
                    acc[m][n] = __builtin_amdgcn_mfma_f32_16x16x32_bf16(
                        af[m], bfr[n], acc[m][n], 0, 0, 0);
            __syncthreads();
        }
    }

    float* Cb = C + z * sC;
    const int lg = lane >> 4;
#pragma unroll
    for (int m = 0; m < 4; ++m)
#pragma unroll
        for (int n = 0; n < 4; ++n) {
            const int col  = n0 + wn * 64 + n * 16 + lr;
            const int rowb = m0 + wm * 64 + m * 16 + lg * 4;
#pragma unroll
            for (int r = 0; r < 4; ++r)
                Cb[(size_t)(rowb + r) * N + col] = acc[m][n][r];
        }
}

// ---------- masked row softmax, z-batched: S fp32 -> P bf16 ----------
// grid (LQ_/4, BG); blockIdx.y selects batch within the group.
__global__ __launch_bounds__(256) void softmax_mask(
    const float* __restrict__ S, const int* __restrict__ mask0,
    u16* __restrict__ P)
{
    const int lane = threadIdx.x & 63;
    const int wave = threadIdx.x >> 6;
    const int row  = blockIdx.x * 4 + wave;          // row within batch
    const size_t zb = blockIdx.y;
    const float* Sr = S + (zb * LQ_ + row) * (size_t)LK_;
    const int* mb   = mask0 + zb * LK_;

    float4 s[8];
    float m = -INFINITY;
#pragma unroll
    for (int i = 0; i < 8; ++i) {
        int k = i * 256 + lane * 4;
        float4 v = *(const float4*)&Sr[k];
        int4 mk  = *(const int4*)&mb[k];
        v.x = mk.x ? v.x : NEG_INF;
        v.y = mk.y ? v.y : NEG_INF;
        v.z = mk.z ? v.z : NEG_INF;
        v.w = mk.w ? v.w : NEG_INF;
        s[i] = v;
        m = fmaxf(m, fmaxf(fmaxf(v.x, v.y), fmaxf(v.z, v.w)));
    }
#pragma unroll
    for (int off = 32; off > 0; off >>= 1)
        m = fmaxf(m, __shfl_xor(m, off, 64));
    float sum = 0.f;
#pragma unroll
    for (int i = 0; i < 8; ++i) {
        s[i].x = __expf(s[i].x - m); sum += s[i].x;
        s[i].y = __expf(s[i].y - m); sum += s[i].y;
        s[i].z = __expf(s[i].z - m); sum += s[i].z;
        s[i].w = __expf(s[i].w - m); sum += s[i].w;
    }
#pragma unroll
    for (int off = 32; off > 0; off >>= 1)
        sum += __shfl_xor(sum, off, 64);
    const float inv = 1.f / sum;
    u16* Pr = P + (zb * LQ_ + row) * (size_t)LK_;
#pragma unroll
    for (int i = 0; i < 8; ++i) {
        int k = i * 256 + lane * 4;
        ushort4 o;
        o.x = f2bf(s[i].x * inv);
        o.y = f2bf(s[i].y * inv);
        o.z = f2bf(s[i].z * inv);
        o.w = f2bf(s[i].w * inv);
        *(ushort4*)&Pr[k] = o;
    }
}

// ---------- fallback (verified R1 fp32 kernel) ----------
__global__ __launch_bounds__(256, 2) void attn_fp32_flash(
    const float* __restrict__ hidden, const float* __restrict__ keys,
    const float* __restrict__ values, const int* __restrict__ mask,
    float* __restrict__ out)
{
    const int lane = threadIdx.x & 63;
    const int wave = threadIdx.x >> 6;
    const int blk  = blockIdx.x;
    const int b    = blk >> 7;
    const int q0   = (blk & 127) * 16 + wave * 4;
    float4 q[4][4]; float4 o[4][4]; float m[4], s[4];
    const float4* hp = (const float4*)(hidden + ((size_t)b * LQ_ + q0) * D_);
#pragma unroll
    for (int r = 0; r < 4; ++r) {
#pragma unroll
        for (int j = 0; j < 4; ++j) {
            q[r][j] = hp[r * 256 + j * 64 + lane];
            o[r][j] = make_float4(0.f, 0.f, 0.f, 0.f);
        }
        m[r] = -INFINITY; s[r] = 0.f;
    }
    const float4* kp = (const float4*)(keys   + (size_t)b * LK_ * D_);
    const float4* vp = (const float4*)(values + (size_t)b * LK_ * D_);
    const int*    mp = mask + b * LK_;
    for (int k = 0; k < LK_; ++k) {
        float4 kv[4];
#pragma unroll
        for (int j = 0; j < 4; ++j) kv[j] = kp[k * 256 + j * 64 + lane];
        float sc[4];
#pragma unroll
        for (int r = 0; r < 4; ++r) {
            float p = 0.f;
#pragma unroll
            for (int j = 0; j < 4; ++j)
                p += q[r][j].x * kv[j].x + q[r][j].y * kv[j].y +
                     q[r][j].z * kv[j].z + q[r][j].w * kv[j].w;
            sc[r] = p;
        }
#pragma unroll
        for (int r = 0; r < 4; ++r)
#pragma unroll
            for (int off = 32; off > 0; off >>= 1)
                sc[r] += __shfl_xor(sc[r], off, 64);
        const int mk = mp[k];
        float4 vv[4];
#pragma unroll
        for (int j = 0; j < 4; ++j) vv[j] = vp[k * 256 + j * 64 + lane];
#pragma unroll
        for (int r = 0; r < 4; ++r) {
            float score = mk ? sc[r] : NEG_INF;
            if (score > m[r]) {
                float scale = __expf(m[r] - score);
                m[r] = score; s[r] *= scale;
#pragma unroll
                for (int j = 0; j < 4; ++j) {
                    o[r][j].x *= scale; o[r][j].y *= scale;
                    o[r][j].z *= scale; o[r][j].w *= scale;
                }
            }
            float e = __expf(score - m[r]);
            s[r] += e;
#pragma unroll
            for (int j = 0; j < 4; ++j) {
                o[r][j].x += e * vv[j].x; o[r][j].y += e * vv[j].y;
                o[r][j].z += e * vv[j].z; o[r][j].w += e * vv[j].w;
            }
        }
    }
    float4* op = (float4*)(out + ((size_t)b * LQ_ + q0) * D_);
#pragma unroll
    for (int r = 0; r < 4; ++r) {
        float inv = 1.f / s[r];
#pragma unroll
        for (int j = 0; j < 4; ++j) {
            float4 t = o[r][j];
            t.x *= inv; t.y *= inv; t.z *= inv; t.w *= inv;
            op[r * 256 + j * 64 + lane] = t;
        }
    }
}

extern "C" void kernel_launch(void* const* d_in, const int* in_sizes, int n_in,
                              void* d_out, int out_size, void* d_ws, size_t ws_size,
                              hipStream_t stream) {
    const float* hidden = (const float*)d_in[0];
    const float* keys   = (const float*)d_in[1];
    const float* values = (const float*)d_in[2];
    const int*   mask   = (const int*)d_in[3];
    float* out = (float*)d_out;
    char* ws = (char*)d_ws;

    const size_t TEN = (size_t)LK_ * D_;          // 2M elems per batch tensor
    const size_t MB  = 1024ull * 1024;

    // choose largest batch-group BG with need = BG * 44 MiB <= ws_size
    int BG = 0;
    for (int g = 8; g >= 1; g >>= 1)
        if ((size_t)g * 44 * MB <= ws_size) { BG = g; break; }

    if (BG == 0) {
        attn_fp32_flash<<<1024, 256, 0, stream>>>(hidden, keys, values, mask, out);
        return;
    }

    // group-scaled buffer layout
    const size_t SZ_BF = (size_t)BG * TEN * 2;            // BG*4 MiB per bf16 tensor
    u16*   Kh = (u16*)(ws);
    u16*   Kl = (u16*)(ws + SZ_BF);
    u16*   VT = (u16*)(ws + 2 * SZ_BF);
    u16*   Qh = (u16*)(ws + 3 * SZ_BF);
    u16*   Ql = (u16*)(ws + 4 * SZ_BF);
    float* S  = (float*)(ws + 5 * SZ_BF);                 // BG*16 MiB
    u16*   P  = (u16*)(ws + 5 * SZ_BF + (size_t)BG * LQ_ * LK_ * 4);

    const int n4 = BG * (int)(TEN / 4);

    for (int bg0 = 0; bg0 < B_; bg0 += BG) {
        const size_t off = (size_t)bg0 * TEN;
        convert_hilo<<<2048, 256, 0, stream>>>(
            (const float4*)(keys + off), (ushort4*)Kh, (ushort4*)Kl, n4);
        transpose_convert<<<dim3(16, 32, BG), 256, 0, stream>>>(
            values + off, VT);
        convert_hilo<<<2048, 256, 0, stream>>>(
            (const float4*)(hidden + off), (ushort4*)Qh, (ushort4*)Ql, n4);

        // S = Qh*Kh^T + Qh*Kl^T + Ql*Kh^T  (per batch in group)
        gemm_bt<3><<<dim3(16, 16, BG), 256, 0, stream>>>(
            Qh, Kh, Qh, Kl, Ql, Kh, S, LK_, D_,
            TEN, TEN, (size_t)LQ_ * LK_);

        softmax_mask<<<dim3(LQ_ / 4, BG), 256, 0, stream>>>(
            S, mask + bg0 * LK_, P);

        // out_chunk = P * VT^T
        gemm_bt<1><<<dim3(8, 16, BG), 256, 0, stream>>>(
            P, VT, P, VT, P, VT, out + off, D_, LK_,
            (size_t)LQ_ * LK_, TEN, TEN);
    }
}

// Round 5
// 436.921 us; speedup vs baseline: 8.4958x; 1.0521x over previous
//
#include <hip/hip_runtime.h>

#define NEG_INF -1e10f
#define B_   8
#define LQ_  2048
#define LK_  2048
#define D_   1024

typedef unsigned int uint;
typedef unsigned short u16;
typedef __bf16 bf16x8_t __attribute__((ext_vector_type(8)));
typedef float f32x4_t __attribute__((ext_vector_type(4)));

// ---------- helpers ----------
__device__ __forceinline__ u16 f2bf(float f) {
    uint u = __float_as_uint(f);
    u += 0x7FFFu + ((u >> 16) & 1u);          // round-to-nearest-even
    return (u16)(u >> 16);
}
__device__ __forceinline__ float bf2f(u16 h) {
    return __uint_as_float(((uint)h) << 16);
}
__device__ __forceinline__ void gload_lds16(const void* g, void* l) {
    __builtin_amdgcn_global_load_lds(
        (const __attribute__((address_space(1))) uint*)g,
        (__attribute__((address_space(3))) uint*)l, 16, 0, 0);
}

// ---------- fp32 -> (hi,lo) bf16 split ----------
__global__ __launch_bounds__(256) void convert_hilo(
    const float4* __restrict__ src, ushort4* __restrict__ hi,
    ushort4* __restrict__ lo, int n4)
{
    int idx = blockIdx.x * 256 + threadIdx.x;
    const int stride = gridDim.x * 256;
    for (; idx < n4; idx += stride) {
        float4 x = src[idx];
        ushort4 h, l;
        h.x = f2bf(x.x); l.x = f2bf(x.x - bf2f(h.x));
        h.y = f2bf(x.y); l.y = f2bf(x.y - bf2f(h.y));
        h.z = f2bf(x.z); l.z = f2bf(x.z - bf2f(h.z));
        h.w = f2bf(x.w); l.w = f2bf(x.w - bf2f(h.w));
        hi[idx] = h; lo[idx] = l;
    }
}

// ---------- V [z][2048][1024] fp32 -> VT [z][1024][2048] bf16 ----------
__global__ __launch_bounds__(256) void transpose_convert(
    const float* __restrict__ V, u16* __restrict__ VT)
{
    __shared__ float tile[64][65];
    const int t  = threadIdx.x;
    const int d0 = blockIdx.x * 64;
    const int k0 = blockIdx.y * 64;
    const float* Vb = V + (size_t)blockIdx.z * (LK_ * D_);
    u16* VTb = VT + (size_t)blockIdx.z * (D_ * LK_);
#pragma unroll
    for (int i = 0; i < 4; ++i) {
        int f = i * 256 + t;
        int r = f >> 4, c4 = f & 15;
        float4 v = *(const float4*)&Vb[(size_t)(k0 + r) * D_ + d0 + c4 * 4];
        tile[r][c4 * 4 + 0] = v.x;
        tile[r][c4 * 4 + 1] = v.y;
        tile[r][c4 * 4 + 2] = v.z;
        tile[r][c4 * 4 + 3] = v.w;
    }
    __syncthreads();
#pragma unroll
    for (int i = 0; i < 4; ++i) {
        int f = i * 256 + t;
        int d = f >> 4, c4 = f & 15;
        ushort4 o;
        o.x = f2bf(tile[c4 * 4 + 0][d]);
        o.y = f2bf(tile[c4 * 4 + 1][d]);
        o.z = f2bf(tile[c4 * 4 + 2][d]);
        o.w = f2bf(tile[c4 * 4 + 3][d]);
        *(ushort4*)&VTb[(size_t)(d0 + d) * LK_ + k0 + c4 * 4] = o;
    }
}

// ---------- fused 3-term QK^T GEMM ----------
// S[m][n] = Qh[m]·Kh[n] + Qh[m]·Kl[n] + Ql[m]·Kh[n]   (all B^T layout, K=1024)
// Stage all 4 operand tiles per K-step; 48 MFMA per step between one barrier pair.
__global__ __launch_bounds__(256, 2) void gemm_qk3(
    const u16* __restrict__ Qh0, const u16* __restrict__ Ql0,
    const u16* __restrict__ Kh0, const u16* __restrict__ Kl0,
    float* __restrict__ C, int N, int K,
    size_t sA, size_t sB, size_t sC)
{
    __shared__ u16 Ahs[128 * 32];
    __shared__ u16 Als[128 * 32];
    __shared__ u16 Bhs[128 * 32];
    __shared__ u16 Bls[128 * 32];
    const int tid  = threadIdx.x;
    const int lane = tid & 63;
    const int w    = tid >> 6;
    const int wm   = w >> 1, wn = w & 1;
    const int m0   = blockIdx.y * 128, n0 = blockIdx.x * 128;
    const size_t z = blockIdx.z;

    const u16* Ah = Qh0 + z * sA;
    const u16* Al = Ql0 + z * sA;
    const u16* Bh = Kh0 + z * sB;
    const u16* Bl = Kl0 + z * sB;

    f32x4_t acc[4][4] = {};
    const int lr = lane & 15;
    const int lk = (lane >> 4) * 8;

    for (int kk = 0; kk < K; kk += 32) {
#pragma unroll
        for (int i = 0; i < 2; ++i) {
            int e = (i * 256 + tid) * 8;
            int r = e >> 5, c = e & 31;
            const size_t goA = (size_t)(m0 + r) * K + kk + c;
            const size_t goB = (size_t)(n0 + r) * K + kk + c;
            const int lo = i * 2048 + w * 512;
            gload_lds16(&Ah[goA], &Ahs[lo]);
            gload_lds16(&Al[goA], &Als[lo]);
            gload_lds16(&Bh[goB], &Bhs[lo]);
            gload_lds16(&Bl[goB], &Bls[lo]);
        }
        __syncthreads();   // drains vmcnt before any wave reads LDS

        bf16x8_t ah[4], al[4], bh[4], bl[4];
#pragma unroll
        for (int m = 0; m < 4; ++m) {
            const int ro = (wm * 64 + m * 16 + lr) * 32 + lk;
            ah[m] = *(const bf16x8_t*)&Ahs[ro];
            al[m] = *(const bf16x8_t*)&Als[ro];
        }
#pragma unroll
        for (int n = 0; n < 4; ++n) {
            const int ro = (wn * 64 + n * 16 + lr) * 32 + lk;
            bh[n] = *(const bf16x8_t*)&Bhs[ro];
            bl[n] = *(const bf16x8_t*)&Bls[ro];
        }
#pragma unroll
        for (int m = 0; m < 4; ++m)
#pragma unroll
            for (int n = 0; n < 4; ++n) {
                acc[m][n] = __builtin_amdgcn_mfma_f32_16x16x32_bf16(
                    ah[m], bh[n], acc[m][n], 0, 0, 0);
                acc[m][n] = __builtin_amdgcn_mfma_f32_16x16x32_bf16(
                    ah[m], bl[n], acc[m][n], 0, 0, 0);
                acc[m][n] = __builtin_amdgcn_mfma_f32_16x16x32_bf16(
                    al[m], bh[n], acc[m][n], 0, 0, 0);
            }
        __syncthreads();   // all reads done before next-tile overwrite
    }

    float* Cb = C + z * sC;
    const int lg = lane >> 4;
#pragma unroll
    for (int m = 0; m < 4; ++m)
#pragma unroll
        for (int n = 0; n < 4; ++n) {
            const int col  = n0 + wn * 64 + n * 16 + lr;
            const int rowb = m0 + wm * 64 + m * 16 + lg * 4;
#pragma unroll
            for (int r = 0; r < 4; ++r)
                Cb[(size_t)(rowb + r) * N + col] = acc[m][n][r];
        }
}

// ---------- plain GEMM (m97 structure): C = A * B^T, z-batched ----------
__global__ __launch_bounds__(256, 2) void gemm_bt1(
    const u16* __restrict__ A0, const u16* __restrict__ B0,
    float* __restrict__ C, int N, int K,
    size_t sA, size_t sB, size_t sC)
{
    __shared__ u16 As[128 * 32];
    __shared__ u16 Bs[128 * 32];
    const int tid  = threadIdx.x;
    const int lane = tid & 63;
    const int w    = tid >> 6;
    const int wm   = w >> 1, wn = w & 1;
    const int m0   = blockIdx.y * 128, n0 = blockIdx.x * 128;
    const size_t z = blockIdx.z;

    const u16* A = A0 + z * sA;
    const u16* B = B0 + z * sB;

    f32x4_t acc[4][4] = {};
    const int lr = lane & 15;
    const int lk = (lane >> 4) * 8;

    for (int kk = 0; kk < K; kk += 32) {
#pragma unroll
        for (int i = 0; i < 2; ++i) {
            int e = (i * 256 + tid) * 8;
            int r = e >> 5, c = e & 31;
            gload_lds16(&A[(size_t)(m0 + r) * K + kk + c], &As[i * 2048 + w * 512]);
            gload_lds16(&B[(size_t)(n0 + r) * K + kk + c], &Bs[i * 2048 + w * 512]);
        }
        __syncthreads();

        bf16x8_t af[4], bfr[4];
#pragma unroll
        for (int m = 0; m < 4; ++m)
            af[m] = *(const bf16x8_t*)&As[(wm * 64 + m * 16 + lr) * 32 + lk];
#pragma unroll
        for (int n = 0; n < 4; ++n)
            bfr[n] = *(const bf16x8_t*)&Bs[(wn * 64 + n * 16 + lr) * 32 + lk];
#pragma unroll
        for (int m = 0; m < 4; ++m)
#pragma unroll
            for (int n = 0; n < 4; ++n)
                acc[m][n] = __builtin_amdgcn_mfma_f32_16x16x32_bf16(
                    af[m], bfr[n], acc[m][n], 0, 0, 0);
        __syncthreads();
    }

    float* Cb = C + z * sC;
    const int lg = lane >> 4;
#pragma unroll
    for (int m = 0; m < 4; ++m)
#pragma unroll
        for (int n = 0; n < 4; ++n) {
            const int col  = n0 + wn * 64 + n * 16 + lr;
            const int rowb = m0 + wm * 64 + m * 16 + lg * 4;
#pragma unroll
            for (int r = 0; r < 4; ++r)
                Cb[(size_t)(rowb + r) * N + col] = acc[m][n][r];
        }
}

// ---------- masked row softmax, z-batched: S fp32 -> P bf16 ----------
__global__ __launch_bounds__(256) void softmax_mask(
    const float* __restrict__ S, const int* __restrict__ mask0,
    u16* __restrict__ P)
{
    const int lane = threadIdx.x & 63;
    const int wave = threadIdx.x >> 6;
    const int row  = blockIdx.x * 4 + wave;          // row within batch
    const size_t zb = blockIdx.y;
    const float* Sr = S + (zb * LQ_ + row) * (size_t)LK_;
    const int* mb   = mask0 + zb * LK_;

    float4 s[8];
    float m = -INFINITY;
#pragma unroll
    for (int i = 0; i < 8; ++i) {
        int k = i * 256 + lane * 4;
        float4 v = *(const float4*)&Sr[k];
        int4 mk  = *(const int4*)&mb[k];
        v.x = mk.x ? v.x : NEG_INF;
        v.y = mk.y ? v.y : NEG_INF;
        v.z = mk.z ? v.z : NEG_INF;
        v.w = mk.w ? v.w : NEG_INF;
        s[i] = v;
        m = fmaxf(m, fmaxf(fmaxf(v.x, v.y), fmaxf(v.z, v.w)));
    }
#pragma unroll
    for (int off = 32; off > 0; off >>= 1)
        m = fmaxf(m, __shfl_xor(m, off, 64));
    float sum = 0.f;
#pragma unroll
    for (int i = 0; i < 8; ++i) {
        s[i].x = __expf(s[i].x - m); sum += s[i].x;
        s[i].y = __expf(s[i].y - m); sum += s[i].y;
        s[i].z = __expf(s[i].z - m); sum += s[i].z;
        s[i].w = __expf(s[i].w - m); sum += s[i].w;
    }
#pragma unroll
    for (int off = 32; off > 0; off >>= 1)
        sum += __shfl_xor(sum, off, 64);
    const float inv = 1.f / sum;
    u16* Pr = P + (zb * LQ_ + row) * (size_t)LK_;
#pragma unroll
    for (int i = 0; i < 8; ++i) {
        int k = i * 256 + lane * 4;
        ushort4 o;
        o.x = f2bf(s[i].x * inv);
        o.y = f2bf(s[i].y * inv);
        o.z = f2bf(s[i].z * inv);
        o.w = f2bf(s[i].w * inv);
        *(ushort4*)&Pr[k] = o;
    }
}

// ---------- fallback (verified R1 fp32 kernel) ----------
__global__ __launch_bounds__(256, 2) void attn_fp32_flash(
    const float* __restrict__ hidden, const float* __restrict__ keys,
    const float* __restrict__ values, const int* __restrict__ mask,
    float* __restrict__ out)
{
    const int lane = threadIdx.x & 63;
    const int wave = threadIdx.x >> 6;
    const int blk  = blockIdx.x;
    const int b    = blk >> 7;
    const int q0   = (blk & 127) * 16 + wave * 4;
    float4 q[4][4]; float4 o[4][4]; float m[4], s[4];
    const float4* hp = (const float4*)(hidden + ((size_t)b * LQ_ + q0) * D_);
#pragma unroll
    for (int r = 0; r < 4; ++r) {
#pragma unroll
        for (int j = 0; j < 4; ++j) {
            q[r][j] = hp[r * 256 + j * 64 + lane];
            o[r][j] = make_float4(0.f, 0.f, 0.f, 0.f);
        }
        m[r] = -INFINITY; s[r] = 0.f;
    }
    const float4* kp = (const float4*)(keys   + (size_t)b * LK_ * D_);
    const float4* vp = (const float4*)(values + (size_t)b * LK_ * D_);
    const int*    mp = mask + b * LK_;
    for (int k = 0; k < LK_; ++k) {
        float4 kv[4];
#pragma unroll
        for (int j = 0; j < 4; ++j) kv[j] = kp[k * 256 + j * 64 + lane];
        float sc[4];
#pragma unroll
        for (int r = 0; r < 4; ++r) {
            float p = 0.f;
#pragma unroll
            for (int j = 0; j < 4; ++j)
                p += q[r][j].x * kv[j].x + q[r][j].y * kv[j].y +
                     q[r][j].z * kv[j].z + q[r][j].w * kv[j].w;
            sc[r] = p;
        }
#pragma unroll
        for (int r = 0; r < 4; ++r)
#pragma unroll
            for (int off = 32; off > 0; off >>= 1)
                sc[r] += __shfl_xor(sc[r], off, 64);
        const int mk = mp[k];
        float4 vv[4];
#pragma unroll
        for (int j = 0; j < 4; ++j) vv[j] = vp[k * 256 + j * 64 + lane];
#pragma unroll
        for (int r = 0; r < 4; ++r) {
            float score = mk ? sc[r] : NEG_INF;
            if (score > m[r]) {
                float scale = __expf(m[r] - score);
                m[r] = score; s[r] *= scale;
#pragma unroll
                for (int j = 0; j < 4; ++j) {
                    o[r][j].x *= scale; o[r][j].y *= scale;
                    o[r][j].z *= scale; o[r][j].w *= scale;
                }
            }
            float e = __expf(score - m[r]);
            s[r] += e;
#pragma unroll
            for (int j = 0; j < 4; ++j) {
                o[r][j].x += e * vv[j].x; o[r][j].y += e * vv[j].y;
                o[r][j].z += e * vv[j].z; o[r][j].w += e * vv[j].w;
            }
        }
    }
    float4* op = (float4*)(out + ((size_t)b * LQ_ + q0) * D_);
#pragma unroll
    for (int r = 0; r < 4; ++r) {
        float inv = 1.f / s[r];
#pragma unroll
        for (int j = 0; j < 4; ++j) {
            float4 t = o[r][j];
            t.x *= inv; t.y *= inv; t.z *= inv; t.w *= inv;
            op[r * 256 + j * 64 + lane] = t;
        }
    }
}

extern "C" void kernel_launch(void* const* d_in, const int* in_sizes, int n_in,
                              void* d_out, int out_size, void* d_ws, size_t ws_size,
                              hipStream_t stream) {
    const float* hidden = (const float*)d_in[0];
    const float* keys   = (const float*)d_in[1];
    const float* values = (const float*)d_in[2];
    const int*   mask   = (const int*)d_in[3];
    float* out = (float*)d_out;
    char* ws = (char*)d_ws;

    const size_t TEN = (size_t)LK_ * D_;          // 2M elems per batch tensor
    const size_t MB  = 1024ull * 1024;

    // choose largest batch-group BG with need = BG * 44 MiB <= ws_size
    int BG = 0;
    for (int g = 8; g >= 1; g >>= 1)
        if ((size_t)g * 44 * MB <= ws_size) { BG = g; break; }

    if (BG == 0) {
        attn_fp32_flash<<<1024, 256, 0, stream>>>(hidden, keys, values, mask, out);
        return;
    }

    // group-scaled buffer layout
    const size_t SZ_BF = (size_t)BG * TEN * 2;            // BG*4 MiB per bf16 tensor
    u16*   Kh = (u16*)(ws);
    u16*   Kl = (u16*)(ws + SZ_BF);
    u16*   VT = (u16*)(ws + 2 * SZ_BF);
    u16*   Qh = (u16*)(ws + 3 * SZ_BF);
    u16*   Ql = (u16*)(ws + 4 * SZ_BF);
    float* S  = (float*)(ws + 5 * SZ_BF);                 // BG*16 MiB
    u16*   P  = (u16*)(ws + 5 * SZ_BF + (size_t)BG * LQ_ * LK_ * 4);

    const int n4 = BG * (int)(TEN / 4);

    for (int bg0 = 0; bg0 < B_; bg0 += BG) {
        const size_t off = (size_t)bg0 * TEN;
        convert_hilo<<<2048, 256, 0, stream>>>(
            (const float4*)(keys + off), (ushort4*)Kh, (ushort4*)Kl, n4);
        transpose_convert<<<dim3(16, 32, BG), 256, 0, stream>>>(
            values + off, VT);
        convert_hilo<<<2048, 256, 0, stream>>>(
            (const float4*)(hidden + off), (ushort4*)Qh, (ushort4*)Ql, n4);

        // S = Qh*Kh^T + Qh*Kl^T + Ql*Kh^T, fused single K-pass
        gemm_qk3<<<dim3(16, 16, BG), 256, 0, stream>>>(
            Qh, Ql, Kh, Kl, S, LK_, D_,
            TEN, TEN, (size_t)LQ_ * LK_);

        softmax_mask<<<dim3(LQ_ / 4, BG), 256, 0, stream>>>(
            S, mask + bg0 * LK_, P);

        // out_chunk = P * VT^T
        gemm_bt1<<<dim3(8, 16, BG), 256, 0, stream>>>(
            P, VT, out + off, D_, LK_,
            (size_t)LQ_ * LK_, TEN, TEN);
    }
}

// Round 6
// 365.253 us; speedup vs baseline: 10.1628x; 1.1962x over previous
//
#include <hip/hip_runtime.h>

#define NEG_INF -1e10f
#define B_   8
#define LQ_  2048
#define LK_  2048
#define D_   1024

typedef unsigned int uint;
typedef unsigned short u16;
typedef _Float16 f16;
typedef _Float16 f16x8_t __attribute__((ext_vector_type(8)));
typedef float f32x4_t __attribute__((ext_vector_type(4)));

// ---------- helpers ----------
__device__ __forceinline__ u16 f2h_bits(float f) {
    f16 h = (f16)f;                            // v_cvt_f16_f32, RTNE
    return __builtin_bit_cast(u16, h);
}
__device__ __forceinline__ float h2f(u16 b) {
    return (float)__builtin_bit_cast(f16, b);
}
__device__ __forceinline__ void gload_lds16(const void* g, void* l) {
    __builtin_amdgcn_global_load_lds(
        (const __attribute__((address_space(1))) uint*)g,
        (__attribute__((address_space(3))) uint*)l, 16, 0, 0);
}

// ---------- fp32 -> (hi,lo) fp16 split (Q path) ----------
__global__ __launch_bounds__(256) void convert_q_hilo(
    const float4* __restrict__ src, ushort4* __restrict__ hi,
    ushort4* __restrict__ lo, int n4)
{
    int idx = blockIdx.x * 256 + threadIdx.x;
    const int stride = gridDim.x * 256;
    for (; idx < n4; idx += stride) {
        float4 x = src[idx];
        ushort4 h, l;
        h.x = f2h_bits(x.x); l.x = f2h_bits(x.x - h2f(h.x));
        h.y = f2h_bits(x.y); l.y = f2h_bits(x.y - h2f(h.y));
        h.z = f2h_bits(x.z); l.z = f2h_bits(x.z - h2f(h.z));
        h.w = f2h_bits(x.w); l.w = f2h_bits(x.w - h2f(h.w));
        hi[idx] = h; lo[idx] = l;
    }
}

// ---------- fp32 -> fp16 (K path, single) ----------
__global__ __launch_bounds__(256) void convert_f16(
    const float4* __restrict__ src, ushort4* __restrict__ dst, int n4)
{
    int idx = blockIdx.x * 256 + threadIdx.x;
    const int stride = gridDim.x * 256;
    for (; idx < n4; idx += stride) {
        float4 x = src[idx];
        ushort4 h;
        h.x = f2h_bits(x.x);
        h.y = f2h_bits(x.y);
        h.z = f2h_bits(x.z);
        h.w = f2h_bits(x.w);
        dst[idx] = h;
    }
}

// ---------- V [z][2048][1024] fp32 -> VT [z][1024][2048] fp16 ----------
__global__ __launch_bounds__(256) void transpose_convert(
    const float* __restrict__ V, u16* __restrict__ VT)
{
    __shared__ float tile[64][65];
    const int t  = threadIdx.x;
    const int d0 = blockIdx.x * 64;
    const int k0 = blockIdx.y * 64;
    const float* Vb = V + (size_t)blockIdx.z * (LK_ * D_);
    u16* VTb = VT + (size_t)blockIdx.z * (D_ * LK_);
#pragma unroll
    for (int i = 0; i < 4; ++i) {
        int f = i * 256 + t;
        int r = f >> 4, c4 = f & 15;
        float4 v = *(const float4*)&Vb[(size_t)(k0 + r) * D_ + d0 + c4 * 4];
        tile[r][c4 * 4 + 0] = v.x;
        tile[r][c4 * 4 + 1] = v.y;
        tile[r][c4 * 4 + 2] = v.z;
        tile[r][c4 * 4 + 3] = v.w;
    }
    __syncthreads();
#pragma unroll
    for (int i = 0; i < 4; ++i) {
        int f = i * 256 + t;
        int d = f >> 4, c4 = f & 15;
        ushort4 o;
        o.x = f2h_bits(tile[c4 * 4 + 0][d]);
        o.y = f2h_bits(tile[c4 * 4 + 1][d]);
        o.z = f2h_bits(tile[c4 * 4 + 2][d]);
        o.w = f2h_bits(tile[c4 * 4 + 3][d]);
        *(ushort4*)&VTb[(size_t)(d0 + d) * LK_ + k0 + c4 * 4] = o;
    }
}

// ---------- fused 2-term QK^T GEMM (fp16) ----------
// S[m][n] = Qh[m]·Kh[n] + Ql[m]·Kh[n]   (B^T layout, K=1024, fp32 accum)
__global__ __launch_bounds__(256, 2) void gemm_qk2(
    const u16* __restrict__ Qh0, const u16* __restrict__ Ql0,
    const u16* __restrict__ Kh0,
    float* __restrict__ C, int N, int K,
    size_t sA, size_t sB, size_t sC)
{
    __shared__ u16 Ahs[128 * 32];
    __shared__ u16 Als[128 * 32];
    __shared__ u16 Bhs[128 * 32];
    const int tid  = threadIdx.x;
    const int lane = tid & 63;
    const int w    = tid >> 6;
    const int wm   = w >> 1, wn = w & 1;
    const int m0   = blockIdx.y * 128, n0 = blockIdx.x * 128;
    const size_t z = blockIdx.z;

    const u16* Ah = Qh0 + z * sA;
    const u16* Al = Ql0 + z * sA;
    const u16* Bh = Kh0 + z * sB;

    f32x4_t acc[4][4] = {};
    const int lr = lane & 15;
    const int lk = (lane >> 4) * 8;

    for (int kk = 0; kk < K; kk += 32) {
#pragma unroll
        for (int i = 0; i < 2; ++i) {
            int e = (i * 256 + tid) * 8;
            int r = e >> 5, c = e & 31;
            const size_t goA = (size_t)(m0 + r) * K + kk + c;
            const size_t goB = (size_t)(n0 + r) * K + kk + c;
            const int lo = i * 2048 + w * 512;
            gload_lds16(&Ah[goA], &Ahs[lo]);
            gload_lds16(&Al[goA], &Als[lo]);
            gload_lds16(&Bh[goB], &Bhs[lo]);
        }
        __syncthreads();   // drains vmcnt before any wave reads LDS

        f16x8_t ah[4], al[4], bh[4];
#pragma unroll
        for (int m = 0; m < 4; ++m) {
            const int ro = (wm * 64 + m * 16 + lr) * 32 + lk;
            ah[m] = *(const f16x8_t*)&Ahs[ro];
            al[m] = *(const f16x8_t*)&Als[ro];
        }
#pragma unroll
        for (int n = 0; n < 4; ++n)
            bh[n] = *(const f16x8_t*)&Bhs[(wn * 64 + n * 16 + lr) * 32 + lk];
#pragma unroll
        for (int m = 0; m < 4; ++m)
#pragma unroll
            for (int n = 0; n < 4; ++n) {
                acc[m][n] = __builtin_amdgcn_mfma_f32_16x16x32_f16(
                    ah[m], bh[n], acc[m][n], 0, 0, 0);
                acc[m][n] = __builtin_amdgcn_mfma_f32_16x16x32_f16(
                    al[m], bh[n], acc[m][n], 0, 0, 0);
            }
        __syncthreads();   // all reads done before next-tile overwrite
    }

    float* Cb = C + z * sC;
    const int lg = lane >> 4;
#pragma unroll
    for (int m = 0; m < 4; ++m)
#pragma unroll
        for (int n = 0; n < 4; ++n) {
            const int col  = n0 + wn * 64 + n * 16 + lr;
            const int rowb = m0 + wm * 64 + m * 16 + lg * 4;
#pragma unroll
            for (int r = 0; r < 4; ++r)
                Cb[(size_t)(rowb + r) * N + col] = acc[m][n][r];
        }
}

// ---------- plain fp16 GEMM (m97 structure): C = A * B^T, z-batched ----------
__global__ __launch_bounds__(256, 2) void gemm_bt1(
    const u16* __restrict__ A0, const u16* __restrict__ B0,
    float* __restrict__ C, int N, int K,
    size_t sA, size_t sB, size_t sC)
{
    __shared__ u16 As[128 * 32];
    __shared__ u16 Bs[128 * 32];
    const int tid  = threadIdx.x;
    const int lane = tid & 63;
    const int w    = tid >> 6;
    const int wm   = w >> 1, wn = w & 1;
    const int m0   = blockIdx.y * 128, n0 = blockIdx.x * 128;
    const size_t z = blockIdx.z;

    const u16* A = A0 + z * sA;
    const u16* B = B0 + z * sB;

    f32x4_t acc[4][4] = {};
    const int lr = lane & 15;
    const int lk = (lane >> 4) * 8;

    for (int kk = 0; kk < K; kk += 32) {
#pragma unroll
        for (int i = 0; i < 2; ++i) {
            int e = (i * 256 + tid) * 8;
            int r = e >> 5, c = e & 31;
            gload_lds16(&A[(size_t)(m0 + r) * K + kk + c], &As[i * 2048 + w * 512]);
            gload_lds16(&B[(size_t)(n0 + r) * K + kk + c], &Bs[i * 2048 + w * 512]);
        }
        __syncthreads();

        f16x8_t af[4], bfr[4];
#pragma unroll
        for (int m = 0; m < 4; ++m)
            af[m] = *(const f16x8_t*)&As[(wm * 64 + m * 16 + lr) * 32 + lk];
#pragma unroll
        for (int n = 0; n < 4; ++n)
            bfr[n] = *(const f16x8_t*)&Bs[(wn * 64 + n * 16 + lr) * 32 + lk];
#pragma unroll
        for (int m = 0; m < 4; ++m)
#pragma unroll
            for (int n = 0; n < 4; ++n)
                acc[m][n] = __builtin_amdgcn_mfma_f32_16x16x32_f16(
                    af[m], bfr[n], acc[m][n], 0, 0, 0);
        __syncthreads();
    }

    float* Cb = C + z * sC;
    const int lg = lane >> 4;
#pragma unroll
    for (int m = 0; m < 4; ++m)
#pragma unroll
        for (int n = 0; n < 4; ++n) {
            const int col  = n0 + wn * 64 + n * 16 + lr;
            const int rowb = m0 + wm * 64 + m * 16 + lg * 4;
#pragma unroll
            for (int r = 0; r < 4; ++r)
                Cb[(size_t)(rowb + r) * N + col] = acc[m][n][r];
        }
}

// ---------- masked row softmax, z-batched: S fp32 -> P fp16 ----------
__global__ __launch_bounds__(256) void softmax_mask(
    const float* __restrict__ S, const int* __restrict__ mask0,
    u16* __restrict__ P)
{
    const int lane = threadIdx.x & 63;
    const int wave = threadIdx.x >> 6;
    const int row  = blockIdx.x * 4 + wave;          // row within batch
    const size_t zb = blockIdx.y;
    const float* Sr = S + (zb * LQ_ + row) * (size_t)LK_;
    const int* mb   = mask0 + zb * LK_;

    float4 s[8];
    float m = -INFINITY;
#pragma unroll
    for (int i = 0; i < 8; ++i) {
        int k = i * 256 + lane * 4;
        float4 v = *(const float4*)&Sr[k];
        int4 mk  = *(const int4*)&mb[k];
        v.x = mk.x ? v.x : NEG_INF;
        v.y = mk.y ? v.y : NEG_INF;
        v.z = mk.z ? v.z : NEG_INF;
        v.w = mk.w ? v.w : NEG_INF;
        s[i] = v;
        m = fmaxf(m, fmaxf(fmaxf(v.x, v.y), fmaxf(v.z, v.w)));
    }
#pragma unroll
    for (int off = 32; off > 0; off >>= 1)
        m = fmaxf(m, __shfl_xor(m, off, 64));
    float sum = 0.f;
#pragma unroll
    for (int i = 0; i < 8; ++i) {
        s[i].x = __expf(s[i].x - m); sum += s[i].x;
        s[i].y = __expf(s[i].y - m); sum += s[i].y;
        s[i].z = __expf(s[i].z - m); sum += s[i].z;
        s[i].w = __expf(s[i].w - m); sum += s[i].w;
    }
#pragma unroll
    for (int off = 32; off > 0; off >>= 1)
        sum += __shfl_xor(sum, off, 64);
    const float inv = 1.f / sum;
    u16* Pr = P + (zb * LQ_ + row) * (size_t)LK_;
#pragma unroll
    for (int i = 0; i < 8; ++i) {
        int k = i * 256 + lane * 4;
        ushort4 o;
        o.x = f2h_bits(s[i].x * inv);
        o.y = f2h_bits(s[i].y * inv);
        o.z = f2h_bits(s[i].z * inv);
        o.w = f2h_bits(s[i].w * inv);
        *(ushort4*)&Pr[k] = o;
    }
}

// ---------- fallback (verified R1 fp32 kernel) ----------
__global__ __launch_bounds__(256, 2) void attn_fp32_flash(
    const float* __restrict__ hidden, const float* __restrict__ keys,
    const float* __restrict__ values, const int* __restrict__ mask,
    float* __restrict__ out)
{
    const int lane = threadIdx.x & 63;
    const int wave = threadIdx.x >> 6;
    const int blk  = blockIdx.x;
    const int b    = blk >> 7;
    const int q0   = (blk & 127) * 16 + wave * 4;
    float4 q[4][4]; float4 o[4][4]; float m[4], s[4];
    const float4* hp = (const float4*)(hidden + ((size_t)b * LQ_ + q0) * D_);
#pragma unroll
    for (int r = 0; r < 4; ++r) {
#pragma unroll
        for (int j = 0; j < 4; ++j) {
            q[r][j] = hp[r * 256 + j * 64 + lane];
            o[r][j] = make_float4(0.f, 0.f, 0.f, 0.f);
        }
        m[r] = -INFINITY; s[r] = 0.f;
    }
    const float4* kp = (const float4*)(keys   + (size_t)b * LK_ * D_);
    const float4* vp = (const float4*)(values + (size_t)b * LK_ * D_);
    const int*    mp = mask + b * LK_;
    for (int k = 0; k < LK_; ++k) {
        float4 kv[4];
#pragma unroll
        for (int j = 0; j < 4; ++j) kv[j] = kp[k * 256 + j * 64 + lane];
        float sc[4];
#pragma unroll
        for (int r = 0; r < 4; ++r) {
            float p = 0.f;
#pragma unroll
            for (int j = 0; j < 4; ++j)
                p += q[r][j].x * kv[j].x + q[r][j].y * kv[j].y +
                     q[r][j].z * kv[j].z + q[r][j].w * kv[j].w;
            sc[r] = p;
        }
#pragma unroll
        for (int r = 0; r < 4; ++r)
#pragma unroll
            for (int off = 32; off > 0; off >>= 1)
                sc[r] += __shfl_xor(sc[r], off, 64);
        const int mk = mp[k];
        float4 vv[4];
#pragma unroll
        for (int j = 0; j < 4; ++j) vv[j] = vp[k * 256 + j * 64 + lane];
#pragma unroll
        for (int r = 0; r < 4; ++r) {
            float score = mk ? sc[r] : NEG_INF;
            if (score > m[r]) {
                float scale = __expf(m[r] - score);
                m[r] = score; s[r] *= scale;
#pragma unroll
                for (int j = 0; j < 4; ++j) {
                    o[r][j].x *= scale; o[r][j].y *= scale;
                    o[r][j].z *= scale; o[r][j].w *= scale;
                }
            }
            float e = __expf(score - m[r]);
            s[r] += e;
#pragma unroll
            for (int j = 0; j < 4; ++j) {
                o[r][j].x += e * vv[j].x; o[r][j].y += e * vv[j].y;
                o[r][j].z += e * vv[j].z; o[r][j].w += e * vv[j].w;
            }
        }
    }
    float4* op = (float4*)(out + ((size_t)b * LQ_ + q0) * D_);
#pragma unroll
    for (int r = 0; r < 4; ++r) {
        float inv = 1.f / s[r];
#pragma unroll
        for (int j = 0; j < 4; ++j) {
            float4 t = o[r][j];
            t.x *= inv; t.y *= inv; t.z *= inv; t.w *= inv;
            op[r * 256 + j * 64 + lane] = t;
        }
    }
}

extern "C" void kernel_launch(void* const* d_in, const int* in_sizes, int n_in,
                              void* d_out, int out_size, void* d_ws, size_t ws_size,
                              hipStream_t stream) {
    const float* hidden = (const float*)d_in[0];
    const float* keys   = (const float*)d_in[1];
    const float* values = (const float*)d_in[2];
    const int*   mask   = (const int*)d_in[3];
    float* out = (float*)d_out;
    char* ws = (char*)d_ws;

    const size_t TEN = (size_t)LK_ * D_;          // 2M elems per batch tensor
    const size_t MB  = 1024ull * 1024;

    // per-batch footprint: Kh 4 + VT 4 + Qh 4 + Ql 4 + S 16 + P 8 = 40 MiB
    int BG = 0;
    for (int g = 8; g >= 1; g >>= 1)
        if ((size_t)g * 40 * MB <= ws_size) { BG = g; break; }

    if (BG == 0) {
        attn_fp32_flash<<<1024, 256, 0, stream>>>(hidden, keys, values, mask, out);
        return;
    }

    const size_t SZ_BF = (size_t)BG * TEN * 2;            // BG*4 MiB per u16 tensor
    u16*   Kh = (u16*)(ws);
    u16*   VT = (u16*)(ws + SZ_BF);
    u16*   Qh = (u16*)(ws + 2 * SZ_BF);
    u16*   Ql = (u16*)(ws + 3 * SZ_BF);
    float* S  = (float*)(ws + 4 * SZ_BF);                 // BG*16 MiB
    u16*   P  = (u16*)(ws + 4 * SZ_BF + (size_t)BG * LQ_ * LK_ * 4);

    const int n4 = BG * (int)(TEN / 4);

    for (int bg0 = 0; bg0 < B_; bg0 += BG) {
        const size_t off = (size_t)bg0 * TEN;
        convert_f16<<<2048, 256, 0, stream>>>(
            (const float4*)(keys + off), (ushort4*)Kh, n4);
        transpose_convert<<<dim3(16, 32, BG), 256, 0, stream>>>(
            values + off, VT);
        convert_q_hilo<<<2048, 256, 0, stream>>>(
            (const float4*)(hidden + off), (ushort4*)Qh, (ushort4*)Ql, n4);

        // S = Qh*Kh^T + Ql*Kh^T  (fp16 inputs, fp32 accum), single K-pass
        gemm_qk2<<<dim3(16, 16, BG), 256, 0, stream>>>(
            Qh, Ql, Kh, S, LK_, D_,
            TEN, TEN, (size_t)LQ_ * LK_);

        softmax_mask<<<dim3(LQ_ / 4, BG), 256, 0, stream>>>(
            S, mask + bg0 * LK_, P);

        // out_chunk = P * VT^T
        gemm_bt1<<<dim3(8, 16, BG), 256, 0, stream>>>(
            P, VT, out + off, D_, LK_,
            (size_t)LQ_ * LK_, TEN, TEN);
    }
}

// Round 7
// 334.263 us; speedup vs baseline: 11.1050x; 1.0927x over previous
//
#include <hip/hip_runtime.h>

#define NEG_INF -1e10f
#define B_   8
#define LQ_  2048
#define LK_  2048
#define D_   1024

typedef unsigned int uint;
typedef unsigned short u16;
typedef _Float16 f16;
typedef _Float16 f16x8_t __attribute__((ext_vector_type(8)));
typedef float f32x4_t __attribute__((ext_vector_type(4)));

// ---------- helpers ----------
__device__ __forceinline__ u16 f2h_bits(float f) {
    f16 h = (f16)f;
    return __builtin_bit_cast(u16, h);
}
__device__ __forceinline__ float h2f(u16 b) {
    return (float)__builtin_bit_cast(f16, b);
}
__device__ __forceinline__ void gload_lds16(const void* g, void* l) {
    __builtin_amdgcn_global_load_lds(
        (const __attribute__((address_space(1))) uint*)g,
        (__attribute__((address_space(3))) uint*)l, 16, 0, 0);
}

// ---------- fp32 -> (hi,lo) fp16 split (Q path) ----------
__global__ __launch_bounds__(256) void convert_q_hilo(
    const float4* __restrict__ src, ushort4* __restrict__ hi,
    ushort4* __restrict__ lo, int n4)
{
    int idx = blockIdx.x * 256 + threadIdx.x;
    const int stride = gridDim.x * 256;
    for (; idx < n4; idx += stride) {
        float4 x = src[idx];
        ushort4 h, l;
        h.x = f2h_bits(x.x); l.x = f2h_bits(x.x - h2f(h.x));
        h.y = f2h_bits(x.y); l.y = f2h_bits(x.y - h2f(h.y));
        h.z = f2h_bits(x.z); l.z = f2h_bits(x.z - h2f(h.z));
        h.w = f2h_bits(x.w); l.w = f2h_bits(x.w - h2f(h.w));
        hi[idx] = h; lo[idx] = l;
    }
}

// ---------- fp32 -> fp16 (K path) ----------
__global__ __launch_bounds__(256) void convert_f16(
    const float4* __restrict__ src, ushort4* __restrict__ dst, int n4)
{
    int idx = blockIdx.x * 256 + threadIdx.x;
    const int stride = gridDim.x * 256;
    for (; idx < n4; idx += stride) {
        float4 x = src[idx];
        ushort4 h;
        h.x = f2h_bits(x.x);
        h.y = f2h_bits(x.y);
        h.z = f2h_bits(x.z);
        h.w = f2h_bits(x.w);
        dst[idx] = h;
    }
}

// ---------- V [z][2048][1024] fp32 -> VT [z][1024][2048] fp16 ----------
__global__ __launch_bounds__(256) void transpose_convert(
    const float* __restrict__ V, u16* __restrict__ VT)
{
    __shared__ float tile[64][65];
    const int t  = threadIdx.x;
    const int d0 = blockIdx.x * 64;
    const int k0 = blockIdx.y * 64;
    const float* Vb = V + (size_t)blockIdx.z * (LK_ * D_);
    u16* VTb = VT + (size_t)blockIdx.z * (D_ * LK_);
#pragma unroll
    for (int i = 0; i < 4; ++i) {
        int f = i * 256 + t;
        int r = f >> 4, c4 = f & 15;
        float4 v = *(const float4*)&Vb[(size_t)(k0 + r) * D_ + d0 + c4 * 4];
        tile[r][c4 * 4 + 0] = v.x;
        tile[r][c4 * 4 + 1] = v.y;
        tile[r][c4 * 4 + 2] = v.z;
        tile[r][c4 * 4 + 3] = v.w;
    }
    __syncthreads();
#pragma unroll
    for (int i = 0; i < 4; ++i) {
        int f = i * 256 + t;
        int d = f >> 4, c4 = f & 15;
        ushort4 o;
        o.x = f2h_bits(tile[c4 * 4 + 0][d]);
        o.y = f2h_bits(tile[c4 * 4 + 1][d]);
        o.z = f2h_bits(tile[c4 * 4 + 2][d]);
        o.w = f2h_bits(tile[c4 * 4 + 3][d]);
        *(ushort4*)&VTb[(size_t)(d0 + d) * LK_ + k0 + c4 * 4] = o;
    }
}

// ===================================================================
// 8-phase counted-vmcnt GEMM, virtual K = 2048 (NT_=64 tiles of BK=32)
//   C = [A0 | A1] * B^T, where A = A0 rows for k<1024, A1 for k>=1024,
//   B column index wraps with bkmask (QK: Kh twice; PV: straight K).
//   NBF=4 -> BN=256 (QK, 128KiB LDS); NBF=2 -> BN=128 (PV, 96KiB).
// Schedule per step t (2 phases): ds_read swizzled frags from buf[t&3],
// stage tile t+3 into buf[(t+3)&3] (dead since step t-1's trailing
// barrier), counted vmcnt(2*PBUF) at step end waits exactly tile t+1.
// ===================================================================
#define BM_  256
#define BK_  32
#define NT_  64

#define DSR(dst, base, off) \
    asm volatile("ds_read_b128 %0, %1 offset:" off : "=v"(dst) : "v"(base))

template<int NBF>
__global__ __launch_bounds__(512, 2) void gemm8p(
    const u16* __restrict__ A0g, const u16* __restrict__ A1g,
    const u16* __restrict__ Bg, float* __restrict__ Cg,
    int lda, int ldb, int ldc, int bkmask,
    size_t szA, size_t szB, size_t szC)
{
    constexpr int BN     = 64 * NBF;
    constexpr int ABYTES = BM_ * BK_ * 2;          // 16384
    constexpr int BBYTES = BN * BK_ * 2;           // 16384 / 8192
    constexpr int BUFSZ  = ABYTES + BBYTES;        // 32768 / 24576
    __shared__ char lds[4 * BUFSZ];

    const int tid  = threadIdx.x;
    const int lane = tid & 63;
    const int w    = tid >> 6;           // 0..7
    const int wm   = w >> 2;             // 0..1
    const int wn   = w & 3;              // 0..3
    const int m0   = blockIdx.y * BM_;
    const int n0   = blockIdx.x * BN;
    const size_t z = blockIdx.z;

    const u16* A0 = A0g + z * szA;
    const u16* A1 = A1g + z * szA;
    const u16* B  = Bg  + z * szB;
    float* C = Cg + z * szC;

    const uint ldsbase = (uint)(size_t)&lds[0];
    const int  lr   = lane & 15;
    // T2 swizzle: chunk' = chunk ^ ((row>>1)&3); per-lane constant parts
    const uint csel = (uint)((((lane >> 4) ^ ((lane >> 1) & 3)) * 16));
    const int  cstg = (((lane & 3) ^ ((lane >> 3) & 3)) * 8);  // stage src chunk (elems)
    const int  rstg = lane >> 2;                                // row within 16-row chunk

    const uint awoff = (uint)(wm * 8192 + lr * 64) + csel;
    const uint bwoff = (uint)(wn * (NBF * 1024) + lr * 64) + csel;

    f32x4_t acc[8][NBF];
#pragma unroll
    for (int m = 0; m < 8; ++m)
#pragma unroll
        for (int n = 0; n < NBF; ++n)
            acc[m][n] = (f32x4_t){0.f, 0.f, 0.f, 0.f};

    // ---- staging lambdas (per wave; LDS dest linear, global src swizzled) ----
    auto stA = [&](int t) {
        const u16* Ab = (t < NT_ / 2) ? A0 : A1;
        const int kc = (t & (NT_ / 2 - 1)) * BK_ + cstg;
        char* dst = lds + (t & 3) * BUFSZ + w * 2048;
        gload_lds16(&Ab[(size_t)(m0 + w * 32 + rstg) * lda + kc], dst);
        gload_lds16(&Ab[(size_t)(m0 + w * 32 + 16 + rstg) * lda + kc], dst + 1024);
    };
    auto stB = [&](int t) {
        const int kc = ((t * BK_) & bkmask) + cstg;
        char* dst = lds + (t & 3) * BUFSZ + ABYTES;
        if constexpr (NBF == 4) {
            gload_lds16(&B[(size_t)(n0 + w * 32 + rstg) * ldb + kc], dst + w * 2048);
            gload_lds16(&B[(size_t)(n0 + w * 32 + 16 + rstg) * ldb + kc], dst + w * 2048 + 1024);
        } else {
            gload_lds16(&B[(size_t)(n0 + w * 16 + rstg) * ldb + kc], dst + w * 1024);
        }
    };

    // ---- prologue: stage tiles 0,1,2; wait tile 0 (counted) ----
    stA(0); stB(0); stA(1); stB(1); stA(2); stB(2);
    if constexpr (NBF == 4) asm volatile("s_waitcnt vmcnt(8)");
    else                    asm volatile("s_waitcnt vmcnt(6)");
    __builtin_amdgcn_s_barrier();

    f16x8_t a[4], b[4];

#define PHASE_A(T, DOSTAGE)                                                   \
    {                                                                         \
        const uint aA = ldsbase + (uint)(((T) & 3) * BUFSZ) + awoff;          \
        const uint aB = ldsbase + (uint)(((T) & 3) * BUFSZ + ABYTES) + bwoff; \
        DSR(a[0], aA, "0");    DSR(a[1], aA, "1024");                         \
        DSR(a[2], aA, "2048"); DSR(a[3], aA, "3072");                         \
        DSR(b[0], aB, "0");                                                   \
        if constexpr (NBF >= 2) DSR(b[1], aB, "1024");                        \
        if constexpr (NBF == 4) { DSR(b[2], aB, "2048"); DSR(b[3], aB, "3072"); } \
        if (DOSTAGE) stA((T) + 3);                                            \
        __builtin_amdgcn_s_barrier();                                         \
        asm volatile("s_waitcnt lgkmcnt(0)");                                 \
        __builtin_amdgcn_sched_barrier(0);                                    \
        __builtin_amdgcn_s_setprio(1);                                        \
        _Pragma("unroll")                                                     \
        for (int mf = 0; mf < 4; ++mf)                                        \
            _Pragma("unroll")                                                 \
            for (int nf = 0; nf < NBF; ++nf)                                  \
                acc[mf][nf] = __builtin_amdgcn_mfma_f32_16x16x32_f16(         \
                    a[mf], b[nf], acc[mf][nf], 0, 0, 0);                      \
        __builtin_amdgcn_s_setprio(0);                                        \
        __builtin_amdgcn_s_barrier();                                         \
    }

#define PHASE_B(T, DOSTAGE, VMASM)                                            \
    {                                                                         \
        const uint aA = ldsbase + (uint)(((T) & 3) * BUFSZ) + awoff;          \
        DSR(a[0], aA, "4096"); DSR(a[1], aA, "5120");                         \
        DSR(a[2], aA, "6144"); DSR(a[3], aA, "7168");                         \
        if (DOSTAGE) stB((T) + 3);                                            \
        __builtin_amdgcn_s_barrier();                                         \
        asm volatile("s_waitcnt lgkmcnt(0)");                                 \
        __builtin_amdgcn_sched_barrier(0);                                    \
        __builtin_amdgcn_s_setprio(1);                                        \
        _Pragma("unroll")                                                     \
        for (int mf = 0; mf < 4; ++mf)                                        \
            _Pragma("unroll")                                                 \
            for (int nf = 0; nf < NBF; ++nf)                                  \
                acc[4 + mf][nf] = __builtin_amdgcn_mfma_f32_16x16x32_f16(     \
                    a[mf], b[nf], acc[4 + mf][nf], 0, 0, 0);                  \
        __builtin_amdgcn_s_setprio(0);                                        \
        VMASM;                                                                \
        __builtin_amdgcn_s_barrier();                                         \
    }

#define VMW do { if constexpr (NBF == 4) asm volatile("s_waitcnt vmcnt(8)"); \
                 else asm volatile("s_waitcnt vmcnt(6)"); } while (0)
#define VMH do { if constexpr (NBF == 4) asm volatile("s_waitcnt vmcnt(4)"); \
                 else asm volatile("s_waitcnt vmcnt(3)"); } while (0)
#define VM0 asm volatile("s_waitcnt vmcnt(0)")
#define VMN do {} while (0)

    // ---- main loop: steps 0..NT_-4 stage tile t+3, counted vmcnt ----
    for (int t = 0; t < NT_ - 3; ++t) {
        PHASE_A(t, true);
        PHASE_B(t, true, VMW);
    }
    // ---- peeled tail: no stages; shrink vmcnt ----
    PHASE_A(NT_ - 3, false); PHASE_B(NT_ - 3, false, VMH);
    PHASE_A(NT_ - 2, false); PHASE_B(NT_ - 2, false, VM0);
    PHASE_A(NT_ - 1, false); PHASE_B(NT_ - 1, false, VMN);

    // ---- epilogue: C write (fp32) ----
    const int cg = lane >> 4;
#pragma unroll
    for (int mf = 0; mf < 8; ++mf)
#pragma unroll
        for (int nf = 0; nf < NBF; ++nf) {
            const int row = m0 + wm * 128 + mf * 16 + cg * 4;
            const int col = n0 + wn * (NBF * 16) + nf * 16 + lr;
#pragma unroll
            for (int r = 0; r < 4; ++r)
                C[(size_t)(row + r) * ldc + col] = acc[mf][nf][r];
        }
}

// ---------- masked row softmax, z-batched: S fp32 -> P fp16 ----------
__global__ __launch_bounds__(256) void softmax_mask(
    const float* __restrict__ S, const int* __restrict__ mask0,
    u16* __restrict__ P)
{
    const int lane = threadIdx.x & 63;
    const int wave = threadIdx.x >> 6;
    const int row  = blockIdx.x * 4 + wave;
    const size_t zb = blockIdx.y;
    const float* Sr = S + (zb * LQ_ + row) * (size_t)LK_;
    const int* mb   = mask0 + zb * LK_;

    float4 s[8];
    float m = -INFINITY;
#pragma unroll
    for (int i = 0; i < 8; ++i) {
        int k = i * 256 + lane * 4;
        float4 v = *(const float4*)&Sr[k];
        int4 mk  = *(const int4*)&mb[k];
        v.x = mk.x ? v.x : NEG_INF;
        v.y = mk.y ? v.y : NEG_INF;
        v.z = mk.z ? v.z : NEG_INF;
        v.w = mk.w ? v.w : NEG_INF;
        s[i] = v;
        m = fmaxf(m, fmaxf(fmaxf(v.x, v.y), fmaxf(v.z, v.w)));
    }
#pragma unroll
    for (int off = 32; off > 0; off >>= 1)
        m = fmaxf(m, __shfl_xor(m, off, 64));
    float sum = 0.f;
#pragma unroll
    for (int i = 0; i < 8; ++i) {
        s[i].x = __expf(s[i].x - m); sum += s[i].x;
        s[i].y = __expf(s[i].y - m); sum += s[i].y;
        s[i].z = __expf(s[i].z - m); sum += s[i].z;
        s[i].w = __expf(s[i].w - m); sum += s[i].w;
    }
#pragma unroll
    for (int off = 32; off > 0; off >>= 1)
        sum += __shfl_xor(sum, off, 64);
    const float inv = 1.f / sum;
    u16* Pr = P + (zb * LQ_ + row) * (size_t)LK_;
#pragma unroll
    for (int i = 0; i < 8; ++i) {
        int k = i * 256 + lane * 4;
        ushort4 o;
        o.x = f2h_bits(s[i].x * inv);
        o.y = f2h_bits(s[i].y * inv);
        o.z = f2h_bits(s[i].z * inv);
        o.w = f2h_bits(s[i].w * inv);
        *(ushort4*)&Pr[k] = o;
    }
}

// ---------- fallback (verified R1 fp32 kernel) ----------
__global__ __launch_bounds__(256, 2) void attn_fp32_flash(
    const float* __restrict__ hidden, const float* __restrict__ keys,
    const float* __restrict__ values, const int* __restrict__ mask,
    float* __restrict__ out)
{
    const int lane = threadIdx.x & 63;
    const int wave = threadIdx.x >> 6;
    const int blk  = blockIdx.x;
    const int b    = blk >> 7;
    const int q0   = (blk & 127) * 16 + wave * 4;
    float4 q[4][4]; float4 o[4][4]; float m[4], s[4];
    const float4* hp = (const float4*)(hidden + ((size_t)b * LQ_ + q0) * D_);
#pragma unroll
    for (int r = 0; r < 4; ++r) {
#pragma unroll
        for (int j = 0; j < 4; ++j) {
            q[r][j] = hp[r * 256 + j * 64 + lane];
            o[r][j] = make_float4(0.f, 0.f, 0.f, 0.f);
        }
        m[r] = -INFINITY; s[r] = 0.f;
    }
    const float4* kp = (const float4*)(keys   + (size_t)b * LK_ * D_);
    const float4* vp = (const float4*)(values + (size_t)b * LK_ * D_);
    const int*    mp = mask + b * LK_;
    for (int k = 0; k < LK_; ++k) {
        float4 kv[4];
#pragma unroll
        for (int j = 0; j < 4; ++j) kv[j] = kp[k * 256 + j * 64 + lane];
        float sc[4];
#pragma unroll
        for (int r = 0; r < 4; ++r) {
            float p = 0.f;
#pragma unroll
            for (int j = 0; j < 4; ++j)
                p += q[r][j].x * kv[j].x + q[r][j].y * kv[j].y +
                     q[r][j].z * kv[j].z + q[r][j].w * kv[j].w;
            sc[r] = p;
        }
#pragma unroll
        for (int r = 0; r < 4; ++r)
#pragma unroll
            for (int off = 32; off > 0; off >>= 1)
                sc[r] += __shfl_xor(sc[r], off, 64);
        const int mk = mp[k];
        float4 vv[4];
#pragma unroll
        for (int j = 0; j < 4; ++j) vv[j] = vp[k * 256 + j * 64 + lane];
#pragma unroll
        for (int r = 0; r < 4; ++r) {
            float score = mk ? sc[r] : NEG_INF;
            if (score > m[r]) {
                float scale = __expf(m[r] - score);
                m[r] = score; s[r] *= scale;
#pragma unroll
                for (int j = 0; j < 4; ++j) {
                    o[r][j].x *= scale; o[r][j].y *= scale;
                    o[r][j].z *= scale; o[r][j].w *= scale;
                }
            }
            float e = __expf(score - m[r]);
            s[r] += e;
#pragma unroll
            for (int j = 0; j < 4; ++j) {
                o[r][j].x += e * vv[j].x; o[r][j].y += e * vv[j].y;
                o[r][j].z += e * vv[j].z; o[r][j].w += e * vv[j].w;
            }
        }
    }
    float4* op = (float4*)(out + ((size_t)b * LQ_ + q0) * D_);
#pragma unroll
    for (int r = 0; r < 4; ++r) {
        float inv = 1.f / s[r];
#pragma unroll
        for (int j = 0; j < 4; ++j) {
            float4 t = o[r][j];
            t.x *= inv; t.y *= inv; t.z *= inv; t.w *= inv;
            op[r * 256 + j * 64 + lane] = t;
        }
    }
}

extern "C" void kernel_launch(void* const* d_in, const int* in_sizes, int n_in,
                              void* d_out, int out_size, void* d_ws, size_t ws_size,
                              hipStream_t stream) {
    const float* hidden = (const float*)d_in[0];
    const float* keys   = (const float*)d_in[1];
    const float* values = (const float*)d_in[2];
    const int*   mask   = (const int*)d_in[3];
    float* out = (float*)d_out;
    char* ws = (char*)d_ws;

    const size_t TEN = (size_t)LK_ * D_;          // 2M elems per batch tensor
    const size_t MB  = 1024ull * 1024;

    // per-batch footprint: Kh 4 + VT 4 + Qh 4 + Ql 4 + S 16 + P 8 = 40 MiB
    int BG = 0;
    for (int g = 8; g >= 1; g >>= 1)
        if ((size_t)g * 40 * MB <= ws_size) { BG = g; break; }

    if (BG == 0) {
        attn_fp32_flash<<<1024, 256, 0, stream>>>(hidden, keys, values, mask, out);
        return;
    }

    const size_t SZ_BF = (size_t)BG * TEN * 2;            // BG*4 MiB per u16 tensor
    u16*   Kh = (u16*)(ws);
    u16*   VT = (u16*)(ws + SZ_BF);
    u16*   Qh = (u16*)(ws + 2 * SZ_BF);
    u16*   Ql = (u16*)(ws + 3 * SZ_BF);
    float* S  = (float*)(ws + 4 * SZ_BF);                 // BG*16 MiB
    u16*   P  = (u16*)(ws + 4 * SZ_BF + (size_t)BG * LQ_ * LK_ * 4);

    const int n4 = BG * (int)(TEN / 4);

    for (int bg0 = 0; bg0 < B_; bg0 += BG) {
        const size_t off = (size_t)bg0 * TEN;
        convert_f16<<<2048, 256, 0, stream>>>(
            (const float4*)(keys + off), (ushort4*)Kh, n4);
        transpose_convert<<<dim3(16, 32, BG), 256, 0, stream>>>(
            values + off, VT);
        convert_q_hilo<<<2048, 256, 0, stream>>>(
            (const float4*)(hidden + off), (ushort4*)Qh, (ushort4*)Ql, n4);

        // S = [Qh|Ql] * [Kh|Kh]^T  — virtual K=2048, 8-phase counted-vmcnt
        gemm8p<4><<<dim3(8, 8, BG), 512, 0, stream>>>(
            Qh, Ql, Kh, S, D_, D_, LK_, 1023,
            TEN, TEN, (size_t)LQ_ * LK_);

        softmax_mask<<<dim3(LQ_ / 4, BG), 256, 0, stream>>>(
            S, mask + bg0 * LK_, P);

        // out = P * VT^T — straight K=2048 via A1 = P+1024, mask 2047
        gemm8p<2><<<dim3(8, 8, BG), 512, 0, stream>>>(
            P, P + 1024, VT, out + off, LK_, LK_, D_, 2047,
            (size_t)LQ_ * LK_, TEN, (size_t)LQ_ * D_);
    }
}